// Round 5
// baseline (304.049 us; speedup 1.0000x reference)
//
#include <hip/hip_runtime.h>
#include <hip/hip_bf16.h>
#include <cstdint>

// Problem constants
#define BB 2
#define SS 2048
#define DD 768
#define HH 12
#define DHH 64
#define DFF 3072
#define MM (BB * SS)   // 4096

typedef __attribute__((ext_vector_type(8))) short bf16x8;
typedef __attribute__((ext_vector_type(4))) float f32x4;
typedef __attribute__((ext_vector_type(16))) float f32x16;
typedef __attribute__((ext_vector_type(4))) unsigned short u16x4;
typedef unsigned int u32;

#define DEV static __device__ __forceinline__

typedef __attribute__((address_space(1))) void AS1void;
typedef __attribute__((address_space(3))) void AS3void;

DEV void async_copy16(const void* g, void* l) {
  __builtin_amdgcn_global_load_lds((AS1void*)g, (AS3void*)l, 16, 0, 0);
}

DEV unsigned short bf16bits(float f) {
  __hip_bfloat16 h = __float2bfloat16(f);
  return *(unsigned short*)&h;
}

DEV u32 pack2(float a, float b) {
  return ((u32)bf16bits(b) << 16) | (u32)bf16bits(a);
}

// ---------------- LayerNorm: fp32 [rows][768] -> bf16 ----------------
__global__ __launch_bounds__(256) void ln_kernel(
    const float* __restrict__ x, const float* __restrict__ gain,
    const float* __restrict__ off, __hip_bfloat16* __restrict__ out)
{
  const int wave = threadIdx.x >> 6;
  const int lane = threadIdx.x & 63;
  const int row = blockIdx.x * 4 + wave;
  const float* xr = x + (size_t)row * DD;

  float4 v[3];
  float s1 = 0.f, s2 = 0.f;
#pragma unroll
  for (int j = 0; j < 3; ++j) {
    v[j] = *(const float4*)(xr + (j * 64 + lane) * 4);
    s1 += v[j].x + v[j].y + v[j].z + v[j].w;
    s2 += v[j].x * v[j].x + v[j].y * v[j].y + v[j].z * v[j].z + v[j].w * v[j].w;
  }
#pragma unroll
  for (int d = 1; d < 64; d <<= 1) {
    s1 += __shfl_xor(s1, d);
    s2 += __shfl_xor(s2, d);
  }
  const float mean = s1 * (1.0f / 768.0f);
  const float var = fmaxf(s2 * (1.0f / 768.0f) - mean * mean, 0.0f);
  const float rs = 1.0f / (sqrtf(var) + 1e-5f);

  unsigned short* orow = (unsigned short*)out + (size_t)row * DD;
#pragma unroll
  for (int j = 0; j < 3; ++j) {
    const int c = (j * 64 + lane) * 4;
    float4 g4 = *(const float4*)(gain + c);
    float4 o4 = *(const float4*)(off + c);
    u16x4 pk;
    pk[0] = bf16bits(g4.x * ((v[j].x - mean) * rs) + o4.x);
    pk[1] = bf16bits(g4.y * ((v[j].y - mean) * rs) + o4.y);
    pk[2] = bf16bits(g4.z * ((v[j].z - mean) * rs) + o4.z);
    pk[3] = bf16bits(g4.w * ((v[j].w - mean) * rs) + o4.w);
    *(u16x4*)(orow + c) = pk;
  }
}

// ---------------- Transpose fp32 [R][C] -> bf16 [C][R] ----------------
__global__ __launch_bounds__(256) void transpose_generic(
    const float* __restrict__ in, __hip_bfloat16* __restrict__ out, int R, int C)
{
  __shared__ float tile[64][65];
  const int c0 = blockIdx.x * 64, r0 = blockIdx.y * 64;
  for (int i = threadIdx.x; i < 4096; i += 256) {
    int r = i >> 6, c = i & 63;
    tile[r][c] = in[(size_t)(r0 + r) * C + c0 + c];
  }
  __syncthreads();
  for (int i = threadIdx.x; i < 4096; i += 256) {
    int c = i >> 6, r = i & 63;
    out[(size_t)(c0 + c) * R + r0 + r] = __float2bfloat16(tile[r][c]);
  }
}

// Wq/Wk/Wv [H][D][DH] -> bf16 WqkvT [2304][768]
__global__ __launch_bounds__(256) void transpose_qkv(
    const float* __restrict__ Wq, const float* __restrict__ Wk,
    const float* __restrict__ Wv, __hip_bfloat16* __restrict__ out)
{
  __shared__ float tile[64][65];
  const int z = blockIdx.z;
  const int p = z / HH, h = z - p * HH;
  const float* in = (p == 0 ? Wq : (p == 1 ? Wk : Wv)) + (size_t)h * DD * DHH;
  const int r0 = blockIdx.y * 64;
  for (int i = threadIdx.x; i < 4096; i += 256) {
    int r = i >> 6, c = i & 63;
    tile[r][c] = in[(size_t)(r0 + r) * DHH + c];
  }
  __syncthreads();
  for (int i = threadIdx.x; i < 4096; i += 256) {
    int c = i >> 6, r = i & 63;
    out[(size_t)(p * DD + h * DHH + c) * DD + r0 + r] = __float2bfloat16(tile[r][c]);
  }
}

// ---------------- GEMM: bf16 A[M,K] x bf16 BT[N,K] ----------------
template<bool RELU, bool OUT_BF16, bool HAS_RES>
__global__ __launch_bounds__(256) void gemm_bt(
    const __hip_bfloat16* __restrict__ A, const __hip_bfloat16* __restrict__ BT,
    const float* __restrict__ bias, const float* __restrict__ res,
    void* __restrict__ outp, int M, int N, int K)
{
  __shared__ __hip_bfloat16 Alds[128 * 32];
  __shared__ __hip_bfloat16 Blds[128 * 32];
  const int tid = threadIdx.x;
  const int wave = tid >> 6;
  const int lane = tid & 63;
  const int fr = lane & 15, fq = lane >> 4;
  const int wr = wave >> 1, wc = wave & 1;
  const int bm = blockIdx.y * 128, bn = blockIdx.x * 128;

  const int srow = tid >> 2;
  const int scol = (tid & 3) * 8;
  const __hip_bfloat16* ag0 = A + (size_t)(bm + srow) * K + scol;
  const __hip_bfloat16* ag1 = A + (size_t)(bm + 64 + srow) * K + scol;
  const __hip_bfloat16* bg0 = BT + (size_t)(bn + srow) * K + scol;
  const __hip_bfloat16* bg1 = BT + (size_t)(bn + 64 + srow) * K + scol;
  __hip_bfloat16* la0 = Alds + wave * 512;
  __hip_bfloat16* la1 = Alds + 2048 + wave * 512;
  __hip_bfloat16* lb0 = Blds + wave * 512;
  __hip_bfloat16* lb1 = Blds + 2048 + wave * 512;

  f32x4 acc[4][4] = {};

  for (int k0 = 0; k0 < K; k0 += 32) {
    async_copy16(ag0 + k0, la0);
    async_copy16(ag1 + k0, la1);
    async_copy16(bg0 + k0, lb0);
    async_copy16(bg1 + k0, lb1);
    __syncthreads();
    bf16x8 af[4], bfr[4];
#pragma unroll
    for (int i = 0; i < 4; ++i)
      af[i] = *(const bf16x8*)(Alds + (wr * 64 + i * 16 + fr) * 32 + fq * 8);
#pragma unroll
    for (int j = 0; j < 4; ++j)
      bfr[j] = *(const bf16x8*)(Blds + (wc * 64 + j * 16 + fr) * 32 + fq * 8);
#pragma unroll
    for (int i = 0; i < 4; ++i)
#pragma unroll
      for (int j = 0; j < 4; ++j)
        acc[i][j] = __builtin_amdgcn_mfma_f32_16x16x32_bf16(af[i], bfr[j], acc[i][j], 0, 0, 0);
    __syncthreads();
  }

#pragma unroll
  for (int j = 0; j < 4; ++j) {
    const int c = bn + wc * 64 + j * 16 + fr;
    const float bv = bias[c];
#pragma unroll
    for (int i = 0; i < 4; ++i) {
#pragma unroll
      for (int r = 0; r < 4; ++r) {
        const int rr = bm + wr * 64 + i * 16 + fq * 4 + r;
        float v = acc[i][j][r] + bv;
        if (RELU) v = fmaxf(v, 0.0f);
        if (HAS_RES) v += res[(size_t)rr * N + c];
        if (OUT_BF16) ((__hip_bfloat16*)outp)[(size_t)rr * N + c] = __float2bfloat16(v);
        else          ((float*)outp)[(size_t)rr * N + c] = v;
      }
    }
  }
}

// ---------------- Flash attention, swapped-QK^T 32x32 ----------------
// 1D grid of 768 blocks x 512 threads (8 warps), ALL co-resident (3 blocks/CU,
// LDS 34.8KB, <=85 VGPR). XCD-aware decode: xcd = id&7 owns 3 (b,h) heads ->
// per-XCD L2 working set ~2.3MB (Q+K+V of 3 heads) -> K direct loads are L2
// hits, V fetched from HBM once. Block covers 64 q rows = two 32-row strips
// (warps 0-3 = strip 0, warps 4-7 = strip 1) sharing the SAME KV tile set and
// the same 4 staged V buffers; within a strip, warps split KV tiles mod 4 with
// private (m,l,O) partials, LSE-combined via LDS at the end. Strip index p is
// permuted per head so per-CU work stays balanced.
__global__ __launch_bounds__(512, 6) void attn_kernel(
    const __hip_bfloat16* __restrict__ qkv, __hip_bfloat16* __restrict__ outp)
{
  const int HD = 3 * DD;   // 2304
  const int id = blockIdx.x;
  const int xcd = id & 7;
  const int j = id >> 3;              // 0..95 within XCD
  const int bh_l = j >> 5;            // 0..2
  const int c32 = j & 31;
  // balanced permutations: p-sums per CU stay near-uniform
  const int p = (bh_l == 0) ? (31 - c32)
              : (bh_l == 1) ? c32
                            : (31 - ((c32 + 16) & 31));
  const int bh = xcd * 3 + bh_l;      // 24 heads = 8 XCD x 3
  const int b = bh / HH, h = bh - (bh / HH) * HH;

  const int q0A = p * 64;             // block covers q in [q0A, q0A+64)
  const int tid = threadIdx.x, w = tid >> 6, lane = tid & 63;
  const int sidx = w >> 2;            // strip 0/1
  const int c = w & 3;                // kv-split index
  const int col = lane & 31, hi = lane >> 5;
  const int q0w = q0A + 32 * sidx;
  const int qg = q0w + col;

  const size_t base = (size_t)b * SS * HD;
  const __hip_bfloat16* Qp = qkv + base + h * DHH;
  const __hip_bfloat16* Kp = qkv + base + DD + h * DHH;
  const unsigned short* Vus = (const unsigned short*)(qkv + base + 2 * DD + h * DHH);

  // LDS: 4 x 8KB swizzled Vt buffers; epilogue reuses as opart[4][32][65] f32
  // (33280B) + ml[4][2][32] f32 (1024B) = 34304 <= 34816.
  __shared__ __align__(16) char sm[34816];

  // Q fragments: lane holds Q row q=qg, k = kc*16 + hi*8 + e
  bf16x8 qf[4];
#pragma unroll
  for (int kc = 0; kc < 4; ++kc)
    qf[kc] = *(const bf16x8*)(Qp + (size_t)qg * HD + kc * 16 + hi * 8);

  f32x16 o0 = {}, o1 = {};
  float mreg = -1e30f, lreg = 0.f;
  const float CS = 0.125f * 1.44269504f;   // (1/sqrt(64)) * log2(e)

  // V staging: 512 threads; thread owns column d=tid&63, t-rows [st8, st8+8)
  const int sd = tid & 63;
  const int st8 = (tid >> 6) * 8;
  const int swz = (sd * 128 + st8 * 2) ^ ((sd & 7) << 4);

  const int ntiles = p + 1;
  const int nrounds = (ntiles + 3) >> 2;
  char* const vt_c = sm + c * 8192;   // warp's compute buffer

  for (int jr = 0; jr < nrounds; ++jr) {
    __syncthreads();   // all PV reads of previous round done
    // ---- cooperative stage: tiles 4*jr+tt -> buffer tt ----
#pragma unroll
    for (int tt = 0; tt < 4; ++tt) {
      const int tw = 4 * jr + tt;
      if (tw < ntiles) {
        const unsigned short* vrow = Vus + (size_t)(tw * 64 + st8) * HD + sd;
        union { unsigned short u[8]; bf16x8 v; } va;
#pragma unroll
        for (int e = 0; e < 8; ++e) va.u[e] = vrow[(size_t)e * HD];
        *(bf16x8*)(sm + tt * 8192 + swz) = va.v;
      }
    }
    __syncthreads();   // Vt buffers ready

    const int tw = 4 * jr + c;
    if (tw < ntiles) {
      const int kv0 = tw * 64;
      // ---- QK^T (swapped): St = K Q^T ; D col = q (lane-local) ----
      f32x16 s0 = {}, s1 = {};
      const __hip_bfloat16* krow0 = Kp + (size_t)(kv0 + col) * HD + hi * 8;
      const __hip_bfloat16* krow1 = Kp + (size_t)(kv0 + 32 + col) * HD + hi * 8;
#pragma unroll
      for (int kc = 0; kc < 4; ++kc) {
        bf16x8 k0 = *(const bf16x8*)(krow0 + kc * 16);
        bf16x8 k1 = *(const bf16x8*)(krow1 + kc * 16);
        s0 = __builtin_amdgcn_mfma_f32_32x32x16_bf16(k0, qf[kc], s0, 0, 0, 0);
        s1 = __builtin_amdgcn_mfma_f32_32x32x16_bf16(k1, qf[kc], s1, 0, 0, 0);
      }
      // ---- causal mask (diagonal tile only; warp-uniform branch) ----
      if (kv0 + 63 > q0w) {
#pragma unroll
        for (int r = 0; r < 16; ++r) {
          const int tl = (r & 3) + 8 * (r >> 2) + 4 * hi;
          s0[r] = (kv0 + tl <= qg) ? s0[r] : -1e30f;
          s1[r] = (kv0 + 32 + tl <= qg) ? s1[r] : -1e30f;
        }
      }
      // ---- online softmax, fully in-register ----
      float mx = s0[0];
#pragma unroll
      for (int r = 1; r < 16; ++r) mx = fmaxf(mx, s0[r]);
#pragma unroll
      for (int r = 0; r < 16; ++r) mx = fmaxf(mx, s1[r]);
      mx = fmaxf(mx, __shfl_xor(mx, 32));
      const float mnew = fmaxf(mreg, mx);
      const float alpha = exp2f((mreg - mnew) * CS);
      mreg = mnew;
      const float mc = mnew * CS;
      float ps = 0.f;
#pragma unroll
      for (int r = 0; r < 16; ++r) {
        const float p0 = exp2f(s0[r] * CS - mc); s0[r] = p0; ps += p0;
        const float p1 = exp2f(s1[r] * CS - mc); s1[r] = p1; ps += p1;
      }
      ps += __shfl_xor(ps, 32);
      lreg = lreg * alpha + ps;
#pragma unroll
      for (int r = 0; r < 16; ++r) { o0[r] *= alpha; o1[r] *= alpha; }

      // ---- pack P rows to bf16 pairs ----
      u32 pk0[4][2], pk1[4][2];
#pragma unroll
      for (int qd = 0; qd < 4; ++qd) {
        pk0[qd][0] = pack2(s0[4 * qd + 0], s0[4 * qd + 1]);
        pk0[qd][1] = pack2(s0[4 * qd + 2], s0[4 * qd + 3]);
        pk1[qd][0] = pack2(s1[4 * qd + 0], s1[4 * qd + 1]);
        pk1[qd][1] = pack2(s1[4 * qd + 2], s1[4 * qd + 3]);
      }
      // ---- PV: O += mfma(Vt-frag (A), P-frag (B)) ----
#pragma unroll
      for (int kc = 0; kc < 4; ++kc) {
        const int qa = 2 * (kc & 1), qb = qa + 1;
        const u32 A0 = (kc < 2) ? pk0[qa][0] : pk1[qa][0];
        const u32 A1 = (kc < 2) ? pk0[qa][1] : pk1[qa][1];
        const u32 B0 = (kc < 2) ? pk0[qb][0] : pk1[qb][0];
        const u32 B1 = (kc < 2) ? pk0[qb][1] : pk1[qb][1];
        const u32 send0 = hi ? A0 : B0;
        const u32 send1 = hi ? A1 : B1;
        const u32 recv0 = __shfl_xor(send0, 32);
        const u32 recv1 = __shfl_xor(send1, 32);
        const u32 su0 = hi ? B0 : A0;
        const u32 su1 = hi ? B1 : A1;
        union { u32 u[4]; bf16x8 v; } pf;
        pf.u[0] = hi ? recv0 : su0;
        pf.u[1] = hi ? recv1 : su1;
        pf.u[2] = hi ? su0 : recv0;
        pf.u[3] = hi ? su1 : recv1;
        const int toff2 = (kc * 16 + hi * 8) * 2;
        const int d0 = col, d1 = 32 + col;
        bf16x8 vfa = *(const bf16x8*)&vt_c[(d0 * 128 + toff2) ^ ((d0 & 7) << 4)];
        bf16x8 vfb = *(const bf16x8*)&vt_c[(d1 * 128 + toff2) ^ ((d1 & 7) << 4)];
        o0 = __builtin_amdgcn_mfma_f32_32x32x16_bf16(vfa, pf.v, o0, 0, 0, 0);
        o1 = __builtin_amdgcn_mfma_f32_32x32x16_bf16(vfb, pf.v, o1, 0, 0, 0);
      }
    }
  }

  // ---- combine the 4 kv-split partials per strip (two LDS phases) ----
  float* opart = (float*)sm;                 // [4][32][65]
  float* mlp   = (float*)(sm + 33280);       // [c][0][q]=m, [c][1][q]=l
#pragma unroll
  for (int s = 0; s < 2; ++s) {
    __syncthreads();   // V reads done (s=0) / prior phase reads done (s=1)
    if (sidx == s) {
#pragma unroll
      for (int r = 0; r < 16; ++r) {
        const int d = (r & 3) + 8 * (r >> 2) + 4 * hi;
        opart[(c * 32 + col) * 65 + d]      = o0[r];
        opart[(c * 32 + col) * 65 + d + 32] = o1[r];
      }
      if (hi == 0) {
        mlp[c * 64 + col]      = mreg;
        mlp[c * 64 + 32 + col] = lreg;
      }
    }
    __syncthreads();
    // all 512 threads: combine + write strip s
    const int q = tid >> 4;            // 0..31
    const int d0 = (tid & 15) * 4;     // 0..60
    float mcv[4], lcv[4];
#pragma unroll
    for (int cc = 0; cc < 4; ++cc) {
      mcv[cc] = mlp[cc * 64 + q];
      lcv[cc] = mlp[cc * 64 + 32 + q];
    }
    float mstar = fmaxf(fmaxf(mcv[0], mcv[1]), fmaxf(mcv[2], mcv[3]));
    float av[4], lstar = 0.f;
#pragma unroll
    for (int cc = 0; cc < 4; ++cc) {
      av[cc] = exp2f((mcv[cc] - mstar) * CS);
      lstar += av[cc] * lcv[cc];
    }
    const float inv = 1.0f / lstar;
    float acc[4] = {};
#pragma unroll
    for (int cc = 0; cc < 4; ++cc) {
      const float a = av[cc];
#pragma unroll
      for (int e = 0; e < 4; ++e)
        acc[e] += a * opart[(cc * 32 + q) * 65 + d0 + e];
    }
    u16x4 w4;
#pragma unroll
    for (int e = 0; e < 4; ++e) w4[e] = bf16bits(acc[e] * inv);
    unsigned short* orow = (unsigned short*)outp +
        (size_t)(b * SS + q0A + 32 * s + q) * DD + h * DHH + d0;
    *(u16x4*)orow = w4;
  }
}

// ---------------- host ----------------
extern "C" void kernel_launch(void* const* d_in, const int* in_sizes, int n_in,
                              void* d_out, int out_size, void* d_ws, size_t ws_size,
                              hipStream_t stream)
{
  (void)in_sizes; (void)n_in; (void)out_size; (void)ws_size;
  const float* X  = (const float*)d_in[0];
  const float* Wq = (const float*)d_in[1];
  const float* bq = (const float*)d_in[2];
  const float* Wk = (const float*)d_in[3];
  const float* bk = (const float*)d_in[4];
  const float* Wv = (const float*)d_in[5];
  const float* bv = (const float*)d_in[6];
  const float* W0 = (const float*)d_in[7];
  const float* b0 = (const float*)d_in[8];
  const float* W1 = (const float*)d_in[9];
  const float* b1 = (const float*)d_in[10];
  const float* W2 = (const float*)d_in[11];
  const float* b2 = (const float*)d_in[12];
  const float* g1 = (const float*)d_in[13];
  const float* o1 = (const float*)d_in[14];
  const float* g2 = (const float*)d_in[15];
  const float* o2 = (const float*)d_in[16];

  char* ws = (char*)d_ws;
  auto alloc = [&](size_t bytes) {
    char* p = ws;
    ws += (bytes + 255) & ~(size_t)255;
    return p;
  };
  __hip_bfloat16* ln1    = (__hip_bfloat16*)alloc((size_t)MM * DD * 2);
  __hip_bfloat16* qkvb16 = (__hip_bfloat16*)alloc((size_t)MM * 3 * DD * 2);
  __hip_bfloat16* attnb  = (__hip_bfloat16*)alloc((size_t)MM * DD * 2);
  float*          hbuf   = (float*)alloc((size_t)MM * DD * 4);
  __hip_bfloat16* ln2    = (__hip_bfloat16*)alloc((size_t)MM * DD * 2);
  __hip_bfloat16* ffn1   = (__hip_bfloat16*)alloc((size_t)MM * DFF * 2);
  __hip_bfloat16* WqkvT  = (__hip_bfloat16*)alloc((size_t)3 * DD * DD * 2);
  __hip_bfloat16* W0T    = (__hip_bfloat16*)alloc((size_t)DD * DD * 2);
  __hip_bfloat16* W1T    = (__hip_bfloat16*)alloc((size_t)DFF * DD * 2);
  __hip_bfloat16* W2T    = (__hip_bfloat16*)alloc((size_t)DD * DFF * 2);
  float*          qkvbias= (float*)alloc((size_t)3 * DD * 4);

  transpose_qkv<<<dim3(1, 12, 36), 256, 0, stream>>>(Wq, Wk, Wv, WqkvT);
  transpose_generic<<<dim3(12, 12), 256, 0, stream>>>(W0, W0T, DD, DD);
  transpose_generic<<<dim3(48, 12), 256, 0, stream>>>(W1, W1T, DD, DFF);
  transpose_generic<<<dim3(12, 48), 256, 0, stream>>>(W2, W2T, DFF, DD);
  hipMemcpyAsync(qkvbias,          bq, DD * 4, hipMemcpyDeviceToDevice, stream);
  hipMemcpyAsync(qkvbias + DD,     bk, DD * 4, hipMemcpyDeviceToDevice, stream);
  hipMemcpyAsync(qkvbias + 2 * DD, bv, DD * 4, hipMemcpyDeviceToDevice, stream);

  ln_kernel<<<MM / 4, 256, 0, stream>>>(X, g1, o1, ln1);
  gemm_bt<false, true, false><<<dim3(3 * DD / 128, MM / 128), 256, 0, stream>>>(
      ln1, WqkvT, qkvbias, nullptr, qkvb16, MM, 3 * DD, DD);
  attn_kernel<<<768, 512, 0, stream>>>(qkvb16, attnb);
  gemm_bt<false, false, true><<<dim3(DD / 128, MM / 128), 256, 0, stream>>>(
      attnb, W0T, b0, X, hbuf, MM, DD, DD);
  ln_kernel<<<MM / 4, 256, 0, stream>>>(hbuf, g2, o2, ln2);
  gemm_bt<true, true, false><<<dim3(DFF / 128, MM / 128), 256, 0, stream>>>(
      ln2, W1T, b1, nullptr, ffn1, MM, DFF, DD);
  gemm_bt<false, false, true><<<dim3(DD / 128, MM / 128), 256, 0, stream>>>(
      ffn1, W2T, b2, hbuf, (float*)d_out, MM, DD, DFF);
}

// Round 6
// 250.560 us; speedup vs baseline: 1.2135x; 1.2135x over previous
//
#include <hip/hip_runtime.h>
#include <hip/hip_bf16.h>
#include <cstdint>

// Problem constants
#define BB 2
#define SS 2048
#define DD 768
#define HH 12
#define DHH 64
#define DFF 3072
#define MM (BB * SS)   // 4096

typedef __attribute__((ext_vector_type(8))) short bf16x8;
typedef __attribute__((ext_vector_type(4))) float f32x4;
typedef __attribute__((ext_vector_type(16))) float f32x16;
typedef __attribute__((ext_vector_type(4))) unsigned short u16x4;
typedef unsigned int u32;

#define DEV static __device__ __forceinline__

typedef __attribute__((address_space(1))) void AS1void;
typedef __attribute__((address_space(3))) void AS3void;

DEV void async_copy16(const void* g, void* l) {
  __builtin_amdgcn_global_load_lds((AS1void*)g, (AS3void*)l, 16, 0, 0);
}

DEV unsigned short bf16bits(float f) {
  __hip_bfloat16 h = __float2bfloat16(f);
  return *(unsigned short*)&h;
}

DEV u32 pack2(float a, float b) {
  return ((u32)bf16bits(b) << 16) | (u32)bf16bits(a);
}

// ---------------- LayerNorm: fp32 [rows][768] -> bf16 ----------------
__global__ __launch_bounds__(256) void ln_kernel(
    const float* __restrict__ x, const float* __restrict__ gain,
    const float* __restrict__ off, __hip_bfloat16* __restrict__ out)
{
  const int wave = threadIdx.x >> 6;
  const int lane = threadIdx.x & 63;
  const int row = blockIdx.x * 4 + wave;
  const float* xr = x + (size_t)row * DD;

  float4 v[3];
  float s1 = 0.f, s2 = 0.f;
#pragma unroll
  for (int j = 0; j < 3; ++j) {
    v[j] = *(const float4*)(xr + (j * 64 + lane) * 4);
    s1 += v[j].x + v[j].y + v[j].z + v[j].w;
    s2 += v[j].x * v[j].x + v[j].y * v[j].y + v[j].z * v[j].z + v[j].w * v[j].w;
  }
#pragma unroll
  for (int d = 1; d < 64; d <<= 1) {
    s1 += __shfl_xor(s1, d);
    s2 += __shfl_xor(s2, d);
  }
  const float mean = s1 * (1.0f / 768.0f);
  const float var = fmaxf(s2 * (1.0f / 768.0f) - mean * mean, 0.0f);
  const float rs = 1.0f / (sqrtf(var) + 1e-5f);

  unsigned short* orow = (unsigned short*)out + (size_t)row * DD;
#pragma unroll
  for (int j = 0; j < 3; ++j) {
    const int c = (j * 64 + lane) * 4;
    float4 g4 = *(const float4*)(gain + c);
    float4 o4 = *(const float4*)(off + c);
    u16x4 pk;
    pk[0] = bf16bits(g4.x * ((v[j].x - mean) * rs) + o4.x);
    pk[1] = bf16bits(g4.y * ((v[j].y - mean) * rs) + o4.y);
    pk[2] = bf16bits(g4.z * ((v[j].z - mean) * rs) + o4.z);
    pk[3] = bf16bits(g4.w * ((v[j].w - mean) * rs) + o4.w);
    *(u16x4*)(orow + c) = pk;
  }
}

// ---------------- Transpose fp32 [R][C] -> bf16 [C][R] ----------------
__global__ __launch_bounds__(256) void transpose_generic(
    const float* __restrict__ in, __hip_bfloat16* __restrict__ out, int R, int C)
{
  __shared__ float tile[64][65];
  const int c0 = blockIdx.x * 64, r0 = blockIdx.y * 64;
  for (int i = threadIdx.x; i < 4096; i += 256) {
    int r = i >> 6, c = i & 63;
    tile[r][c] = in[(size_t)(r0 + r) * C + c0 + c];
  }
  __syncthreads();
  for (int i = threadIdx.x; i < 4096; i += 256) {
    int c = i >> 6, r = i & 63;
    out[(size_t)(c0 + c) * R + r0 + r] = __float2bfloat16(tile[r][c]);
  }
}

// Wq/Wk/Wv [H][D][DH] -> bf16 WqkvT [2304][768]
__global__ __launch_bounds__(256) void transpose_qkv(
    const float* __restrict__ Wq, const float* __restrict__ Wk,
    const float* __restrict__ Wv, __hip_bfloat16* __restrict__ out)
{
  __shared__ float tile[64][65];
  const int z = blockIdx.z;
  const int p = z / HH, h = z - p * HH;
  const float* in = (p == 0 ? Wq : (p == 1 ? Wk : Wv)) + (size_t)h * DD * DHH;
  const int r0 = blockIdx.y * 64;
  for (int i = threadIdx.x; i < 4096; i += 256) {
    int r = i >> 6, c = i & 63;
    tile[r][c] = in[(size_t)(r0 + r) * DHH + c];
  }
  __syncthreads();
  for (int i = threadIdx.x; i < 4096; i += 256) {
    int c = i >> 6, r = i & 63;
    out[(size_t)(p * DD + h * DHH + c) * DD + r0 + r] = __float2bfloat16(tile[r][c]);
  }
}

// ---------------- GEMM: bf16 A[M,K] x bf16 BT[N,K] ----------------
template<bool RELU, bool OUT_BF16, bool HAS_RES>
__global__ __launch_bounds__(256) void gemm_bt(
    const __hip_bfloat16* __restrict__ A, const __hip_bfloat16* __restrict__ BT,
    const float* __restrict__ bias, const float* __restrict__ res,
    void* __restrict__ outp, int M, int N, int K)
{
  __shared__ __hip_bfloat16 Alds[128 * 32];
  __shared__ __hip_bfloat16 Blds[128 * 32];
  const int tid = threadIdx.x;
  const int wave = tid >> 6;
  const int lane = tid & 63;
  const int fr = lane & 15, fq = lane >> 4;
  const int wr = wave >> 1, wc = wave & 1;
  const int bm = blockIdx.y * 128, bn = blockIdx.x * 128;

  const int srow = tid >> 2;
  const int scol = (tid & 3) * 8;
  const __hip_bfloat16* ag0 = A + (size_t)(bm + srow) * K + scol;
  const __hip_bfloat16* ag1 = A + (size_t)(bm + 64 + srow) * K + scol;
  const __hip_bfloat16* bg0 = BT + (size_t)(bn + srow) * K + scol;
  const __hip_bfloat16* bg1 = BT + (size_t)(bn + 64 + srow) * K + scol;
  __hip_bfloat16* la0 = Alds + wave * 512;
  __hip_bfloat16* la1 = Alds + 2048 + wave * 512;
  __hip_bfloat16* lb0 = Blds + wave * 512;
  __hip_bfloat16* lb1 = Blds + 2048 + wave * 512;

  f32x4 acc[4][4] = {};

  for (int k0 = 0; k0 < K; k0 += 32) {
    async_copy16(ag0 + k0, la0);
    async_copy16(ag1 + k0, la1);
    async_copy16(bg0 + k0, lb0);
    async_copy16(bg1 + k0, lb1);
    __syncthreads();
    bf16x8 af[4], bfr[4];
#pragma unroll
    for (int i = 0; i < 4; ++i)
      af[i] = *(const bf16x8*)(Alds + (wr * 64 + i * 16 + fr) * 32 + fq * 8);
#pragma unroll
    for (int j = 0; j < 4; ++j)
      bfr[j] = *(const bf16x8*)(Blds + (wc * 64 + j * 16 + fr) * 32 + fq * 8);
#pragma unroll
    for (int i = 0; i < 4; ++i)
#pragma unroll
      for (int j = 0; j < 4; ++j)
        acc[i][j] = __builtin_amdgcn_mfma_f32_16x16x32_bf16(af[i], bfr[j], acc[i][j], 0, 0, 0);
    __syncthreads();
  }

#pragma unroll
  for (int j = 0; j < 4; ++j) {
    const int c = bn + wc * 64 + j * 16 + fr;
    const float bv = bias[c];
#pragma unroll
    for (int i = 0; i < 4; ++i) {
#pragma unroll
      for (int r = 0; r < 4; ++r) {
        const int rr = bm + wr * 64 + i * 16 + fq * 4 + r;
        float v = acc[i][j][r] + bv;
        if (RELU) v = fmaxf(v, 0.0f);
        if (HAS_RES) v += res[(size_t)rr * N + c];
        if (OUT_BF16) ((__hip_bfloat16*)outp)[(size_t)rr * N + c] = __float2bfloat16(v);
        else          ((float*)outp)[(size_t)rr * N + c] = v;
      }
    }
  }
}

// ---------------- Flash attention, swapped-QK^T 32x32 ----------------
// 768 blocks x 512 threads (8 warps). XCD-aware decode: xcd = id&7 owns 3
// (b,h) heads -> per-XCD L2 working set ~2.3MB -> K/V fetched from HBM ~once.
// Block covers 64 q rows = two 32-row strips (warps 0-3 / 4-7) sharing the
// SAME KV tile set; within a strip warps split KV tiles mod 4 with private
// (m,l,O), LSE-combined via LDS at the end. BOTH K and V are cooperatively
// staged into XOR-swizzled LDS (coalesced global loads; conflict-light
// ds_read_b128). launch_bounds(512,4): 128-VGPR cap, no spill (state ~110).
__global__ __launch_bounds__(512, 4) void attn_kernel(
    const __hip_bfloat16* __restrict__ qkv, __hip_bfloat16* __restrict__ outp)
{
  const int HD = 3 * DD;   // 2304
  const int id = blockIdx.x;
  const int xcd = id & 7;
  const int j = id >> 3;              // 0..95 within XCD
  const int bh_l = j >> 5;            // 0..2
  const int c32 = j & 31;
  // balanced permutations: p-sums per CU stay near-uniform
  const int p = (bh_l == 0) ? (31 - c32)
              : (bh_l == 1) ? c32
                            : (31 - ((c32 + 16) & 31));
  const int bh = xcd * 3 + bh_l;      // 24 heads = 8 XCD x 3
  const int b = bh / HH, h = bh - (bh / HH) * HH;

  const int q0A = p * 64;             // block covers q in [q0A, q0A+64)
  const int tid = threadIdx.x, w = tid >> 6, lane = tid & 63;
  const int sidx = w >> 2;            // strip 0/1
  const int c = w & 3;                // kv-split index
  const int col = lane & 31, hi = lane >> 5;
  const int q0w = q0A + 32 * sidx;
  const int qg = q0w + col;

  const size_t base = (size_t)b * SS * HD;
  const __hip_bfloat16* Qp = qkv + base + h * DHH;
  const __hip_bfloat16* Kp = qkv + base + DD + h * DHH;
  const unsigned short* Vus = (const unsigned short*)(qkv + base + 2 * DD + h * DHH);

  // LDS: 4 x 8KB swizzled Vt buffers [0,32K) + 4 x 8KB swizzled K buffers
  // [32K,64K). Epilogue reuses [0, 34304) as opart[4][32][65] f32 + ml.
  __shared__ __align__(16) char sm[65536];
  char* const smV = sm;
  char* const smK = sm + 32768;

  // Q fragments: lane holds Q row q=qg, k = kc*16 + hi*8 + e
  bf16x8 qf[4];
#pragma unroll
  for (int kc = 0; kc < 4; ++kc)
    qf[kc] = *(const bf16x8*)(Qp + (size_t)qg * HD + kc * 16 + hi * 8);

  f32x16 o0 = {}, o1 = {};
  float mreg = -1e30f, lreg = 0.f;
  const float CS = 0.125f * 1.44269504f;   // (1/sqrt(64)) * log2(e)

  // V staging (transposed): thread owns column d=tid&63, t-rows [st8, st8+8)
  const int sd = tid & 63;
  const int st8 = (tid >> 6) * 8;
  const int vswz = (sd * 128 + st8 * 2) ^ ((sd & 7) << 4);
  // K staging (row-major): thread owns row kr=tid>>3, d-chunk kd8=(tid&7)*8
  const int kr = tid >> 3;
  const int kd8 = (tid & 7) * 8;
  const int kswz = (kr * 128 + kd8 * 2) ^ ((kr & 7) << 4);

  const int ntiles = p + 1;
  const int nrounds = (ntiles + 3) >> 2;
  char* const vt_c = smV + c * 8192;   // warp's compute buffers
  char* const kt_c = smK + c * 8192;

  for (int jr = 0; jr < nrounds; ++jr) {
    __syncthreads();   // all reads of previous round done
    // ---- cooperative stage: tiles 4*jr+tt -> buffer tt ----
#pragma unroll
    for (int tt = 0; tt < 4; ++tt) {
      const int tw = 4 * jr + tt;
      if (tw < ntiles) {
        // V transposed gather (coalesced across lanes per element)
        const unsigned short* vrow = Vus + (size_t)(tw * 64 + st8) * HD + sd;
        union { unsigned short u[8]; bf16x8 v; } va;
#pragma unroll
        for (int e = 0; e < 8; ++e) va.u[e] = vrow[(size_t)e * HD];
        *(bf16x8*)(smV + tt * 8192 + vswz) = va.v;
        // K row-major copy (fully coalesced b128)
        *(bf16x8*)(smK + tt * 8192 + kswz) =
            *(const bf16x8*)(Kp + (size_t)(tw * 64 + kr) * HD + kd8);
      }
    }
    __syncthreads();   // buffers ready

    const int tw = 4 * jr + c;
    if (tw < ntiles) {
      const int kv0 = tw * 64;
      // ---- QK^T (swapped): St = K Q^T ; D col = q (lane-local) ----
      f32x16 s0 = {}, s1 = {};
#pragma unroll
      for (int kc = 0; kc < 4; ++kc) {
        const int koff2 = (kc * 16 + hi * 8) * 2;
        bf16x8 k0 = *(const bf16x8*)&kt_c[(col * 128 + koff2) ^ ((col & 7) << 4)];
        bf16x8 k1 = *(const bf16x8*)&kt_c[((32 + col) * 128 + koff2) ^ ((col & 7) << 4)];
        s0 = __builtin_amdgcn_mfma_f32_32x32x16_bf16(k0, qf[kc], s0, 0, 0, 0);
        s1 = __builtin_amdgcn_mfma_f32_32x32x16_bf16(k1, qf[kc], s1, 0, 0, 0);
      }
      // ---- causal mask (diagonal tile only; warp-uniform branch) ----
      if (kv0 + 63 > q0w) {
#pragma unroll
        for (int r = 0; r < 16; ++r) {
          const int tl = (r & 3) + 8 * (r >> 2) + 4 * hi;
          s0[r] = (kv0 + tl <= qg) ? s0[r] : -1e30f;
          s1[r] = (kv0 + 32 + tl <= qg) ? s1[r] : -1e30f;
        }
      }
      // ---- online softmax, fully in-register ----
      float mx = s0[0];
#pragma unroll
      for (int r = 1; r < 16; ++r) mx = fmaxf(mx, s0[r]);
#pragma unroll
      for (int r = 0; r < 16; ++r) mx = fmaxf(mx, s1[r]);
      mx = fmaxf(mx, __shfl_xor(mx, 32));
      const float mnew = fmaxf(mreg, mx);
      const float alpha = exp2f((mreg - mnew) * CS);
      mreg = mnew;
      const float mc = mnew * CS;
      float ps = 0.f;
#pragma unroll
      for (int r = 0; r < 16; ++r) {
        const float p0 = exp2f(s0[r] * CS - mc); s0[r] = p0; ps += p0;
        const float p1 = exp2f(s1[r] * CS - mc); s1[r] = p1; ps += p1;
      }
      ps += __shfl_xor(ps, 32);
      lreg = lreg * alpha + ps;
#pragma unroll
      for (int r = 0; r < 16; ++r) { o0[r] *= alpha; o1[r] *= alpha; }

      // ---- pack P rows to bf16 pairs ----
      u32 pk0[4][2], pk1[4][2];
#pragma unroll
      for (int qd = 0; qd < 4; ++qd) {
        pk0[qd][0] = pack2(s0[4 * qd + 0], s0[4 * qd + 1]);
        pk0[qd][1] = pack2(s0[4 * qd + 2], s0[4 * qd + 3]);
        pk1[qd][0] = pack2(s1[4 * qd + 0], s1[4 * qd + 1]);
        pk1[qd][1] = pack2(s1[4 * qd + 2], s1[4 * qd + 3]);
      }
      // ---- PV: O += mfma(Vt-frag (A), P-frag (B)) ----
#pragma unroll
      for (int kc = 0; kc < 4; ++kc) {
        const int qa = 2 * (kc & 1), qb = qa + 1;
        const u32 A0 = (kc < 2) ? pk0[qa][0] : pk1[qa][0];
        const u32 A1 = (kc < 2) ? pk0[qa][1] : pk1[qa][1];
        const u32 B0 = (kc < 2) ? pk0[qb][0] : pk1[qb][0];
        const u32 B1 = (kc < 2) ? pk0[qb][1] : pk1[qb][1];
        const u32 send0 = hi ? A0 : B0;
        const u32 send1 = hi ? A1 : B1;
        const u32 recv0 = __shfl_xor(send0, 32);
        const u32 recv1 = __shfl_xor(send1, 32);
        const u32 su0 = hi ? B0 : A0;
        const u32 su1 = hi ? B1 : A1;
        union { u32 u[4]; bf16x8 v; } pf;
        pf.u[0] = hi ? recv0 : su0;
        pf.u[1] = hi ? recv1 : su1;
        pf.u[2] = hi ? su0 : recv0;
        pf.u[3] = hi ? su1 : recv1;
        const int toff2 = (kc * 16 + hi * 8) * 2;
        const int d0 = col, d1 = 32 + col;
        bf16x8 vfa = *(const bf16x8*)&vt_c[(d0 * 128 + toff2) ^ ((d0 & 7) << 4)];
        bf16x8 vfb = *(const bf16x8*)&vt_c[(d1 * 128 + toff2) ^ ((d1 & 7) << 4)];
        o0 = __builtin_amdgcn_mfma_f32_32x32x16_bf16(vfa, pf.v, o0, 0, 0, 0);
        o1 = __builtin_amdgcn_mfma_f32_32x32x16_bf16(vfb, pf.v, o1, 0, 0, 0);
      }
    }
  }

  // ---- combine the 4 kv-split partials per strip (two LDS phases) ----
  float* opart = (float*)sm;                 // [4][32][65]
  float* mlp   = (float*)(sm + 33280);       // [c][0][q]=m, [c][1][q]=l
#pragma unroll
  for (int s = 0; s < 2; ++s) {
    __syncthreads();   // buffer reads done (s=0) / prior phase reads (s=1)
    if (sidx == s) {
#pragma unroll
      for (int r = 0; r < 16; ++r) {
        const int d = (r & 3) + 8 * (r >> 2) + 4 * hi;
        opart[(c * 32 + col) * 65 + d]      = o0[r];
        opart[(c * 32 + col) * 65 + d + 32] = o1[r];
      }
      if (hi == 0) {
        mlp[c * 64 + col]      = mreg;
        mlp[c * 64 + 32 + col] = lreg;
      }
    }
    __syncthreads();
    // all 512 threads: combine + write strip s
    const int q = tid >> 4;            // 0..31
    const int d0 = (tid & 15) * 4;     // 0..60
    float mcv[4], lcv[4];
#pragma unroll
    for (int cc = 0; cc < 4; ++cc) {
      mcv[cc] = mlp[cc * 64 + q];
      lcv[cc] = mlp[cc * 64 + 32 + q];
    }
    float mstar = fmaxf(fmaxf(mcv[0], mcv[1]), fmaxf(mcv[2], mcv[3]));
    float av[4], lstar = 0.f;
#pragma unroll
    for (int cc = 0; cc < 4; ++cc) {
      av[cc] = exp2f((mcv[cc] - mstar) * CS);
      lstar += av[cc] * lcv[cc];
    }
    const float inv = 1.0f / lstar;
    float acc[4] = {};
#pragma unroll
    for (int cc = 0; cc < 4; ++cc) {
      const float a = av[cc];
#pragma unroll
      for (int e = 0; e < 4; ++e)
        acc[e] += a * opart[(cc * 32 + q) * 65 + d0 + e];
    }
    u16x4 w4;
#pragma unroll
    for (int e = 0; e < 4; ++e) w4[e] = bf16bits(acc[e] * inv);
    unsigned short* orow = (unsigned short*)outp +
        (size_t)(b * SS + q0A + 32 * s + q) * DD + h * DHH + d0;
    *(u16x4*)orow = w4;
  }
}

// ---------------- host ----------------
extern "C" void kernel_launch(void* const* d_in, const int* in_sizes, int n_in,
                              void* d_out, int out_size, void* d_ws, size_t ws_size,
                              hipStream_t stream)
{
  (void)in_sizes; (void)n_in; (void)out_size; (void)ws_size;
  const float* X  = (const float*)d_in[0];
  const float* Wq = (const float*)d_in[1];
  const float* bq = (const float*)d_in[2];
  const float* Wk = (const float*)d_in[3];
  const float* bk = (const float*)d_in[4];
  const float* Wv = (const float*)d_in[5];
  const float* bv = (const float*)d_in[6];
  const float* W0 = (const float*)d_in[7];
  const float* b0 = (const float*)d_in[8];
  const float* W1 = (const float*)d_in[9];
  const float* b1 = (const float*)d_in[10];
  const float* W2 = (const float*)d_in[11];
  const float* b2 = (const float*)d_in[12];
  const float* g1 = (const float*)d_in[13];
  const float* o1 = (const float*)d_in[14];
  const float* g2 = (const float*)d_in[15];
  const float* o2 = (const float*)d_in[16];

  char* ws = (char*)d_ws;
  auto alloc = [&](size_t bytes) {
    char* p = ws;
    ws += (bytes + 255) & ~(size_t)255;
    return p;
  };
  __hip_bfloat16* ln1    = (__hip_bfloat16*)alloc((size_t)MM * DD * 2);
  __hip_bfloat16* qkvb16 = (__hip_bfloat16*)alloc((size_t)MM * 3 * DD * 2);
  __hip_bfloat16* attnb  = (__hip_bfloat16*)alloc((size_t)MM * DD * 2);
  float*          hbuf   = (float*)alloc((size_t)MM * DD * 4);
  __hip_bfloat16* ln2    = (__hip_bfloat16*)alloc((size_t)MM * DD * 2);
  __hip_bfloat16* ffn1   = (__hip_bfloat16*)alloc((size_t)MM * DFF * 2);
  __hip_bfloat16* WqkvT  = (__hip_bfloat16*)alloc((size_t)3 * DD * DD * 2);
  __hip_bfloat16* W0T    = (__hip_bfloat16*)alloc((size_t)DD * DD * 2);
  __hip_bfloat16* W1T    = (__hip_bfloat16*)alloc((size_t)DFF * DD * 2);
  __hip_bfloat16* W2T    = (__hip_bfloat16*)alloc((size_t)DD * DFF * 2);
  float*          qkvbias= (float*)alloc((size_t)3 * DD * 4);

  transpose_qkv<<<dim3(1, 12, 36), 256, 0, stream>>>(Wq, Wk, Wv, WqkvT);
  transpose_generic<<<dim3(12, 12), 256, 0, stream>>>(W0, W0T, DD, DD);
  transpose_generic<<<dim3(48, 12), 256, 0, stream>>>(W1, W1T, DD, DFF);
  transpose_generic<<<dim3(12, 48), 256, 0, stream>>>(W2, W2T, DFF, DD);
  hipMemcpyAsync(qkvbias,          bq, DD * 4, hipMemcpyDeviceToDevice, stream);
  hipMemcpyAsync(qkvbias + DD,     bk, DD * 4, hipMemcpyDeviceToDevice, stream);
  hipMemcpyAsync(qkvbias + 2 * DD, bv, DD * 4, hipMemcpyDeviceToDevice, stream);

  ln_kernel<<<MM / 4, 256, 0, stream>>>(X, g1, o1, ln1);
  gemm_bt<false, true, false><<<dim3(3 * DD / 128, MM / 128), 256, 0, stream>>>(
      ln1, WqkvT, qkvbias, nullptr, qkvb16, MM, 3 * DD, DD);
  attn_kernel<<<768, 512, 0, stream>>>(qkvb16, attnb);
  gemm_bt<false, false, true><<<dim3(DD / 128, MM / 128), 256, 0, stream>>>(
      attnb, W0T, b0, X, hbuf, MM, DD, DD);
  ln_kernel<<<MM / 4, 256, 0, stream>>>(hbuf, g2, o2, ln2);
  gemm_bt<true, true, false><<<dim3(DFF / 128, MM / 128), 256, 0, stream>>>(
      ln2, W1T, b1, nullptr, ffn1, MM, DFF, DD);
  gemm_bt<false, false, true><<<dim3(DD / 128, MM / 128), 256, 0, stream>>>(
      ffn1, W2T, b2, hbuf, (float*)d_out, MM, DD, DFF);
}

// Round 7
// 228.490 us; speedup vs baseline: 1.3307x; 1.0966x over previous
//
#include <hip/hip_runtime.h>
#include <hip/hip_bf16.h>
#include <cstdint>

// Problem constants
#define BB 2
#define SS 2048
#define DD 768
#define HH 12
#define DHH 64
#define DFF 3072
#define MM (BB * SS)   // 4096

typedef __attribute__((ext_vector_type(8))) short bf16x8;
typedef __attribute__((ext_vector_type(4))) float f32x4;
typedef __attribute__((ext_vector_type(16))) float f32x16;
typedef __attribute__((ext_vector_type(4))) unsigned short u16x4;
typedef unsigned int u32;

#define DEV static __device__ __forceinline__

typedef __attribute__((address_space(1))) void AS1void;
typedef __attribute__((address_space(3))) void AS3void;

DEV void async_copy16(const void* g, void* l) {
  __builtin_amdgcn_global_load_lds((AS1void*)g, (AS3void*)l, 16, 0, 0);
}

DEV unsigned short bf16bits(float f) {
  __hip_bfloat16 h = __float2bfloat16(f);
  return *(unsigned short*)&h;
}

DEV u32 pack2(float a, float b) {
  return ((u32)bf16bits(b) << 16) | (u32)bf16bits(a);
}

// ---------------- LayerNorm: fp32 [rows][768] -> bf16 ----------------
__global__ __launch_bounds__(256) void ln_kernel(
    const float* __restrict__ x, const float* __restrict__ gain,
    const float* __restrict__ off, __hip_bfloat16* __restrict__ out)
{
  const int wave = threadIdx.x >> 6;
  const int lane = threadIdx.x & 63;
  const int row = blockIdx.x * 4 + wave;
  const float* xr = x + (size_t)row * DD;

  float4 v[3];
  float s1 = 0.f, s2 = 0.f;
#pragma unroll
  for (int j = 0; j < 3; ++j) {
    v[j] = *(const float4*)(xr + (j * 64 + lane) * 4);
    s1 += v[j].x + v[j].y + v[j].z + v[j].w;
    s2 += v[j].x * v[j].x + v[j].y * v[j].y + v[j].z * v[j].z + v[j].w * v[j].w;
  }
#pragma unroll
  for (int d = 1; d < 64; d <<= 1) {
    s1 += __shfl_xor(s1, d);
    s2 += __shfl_xor(s2, d);
  }
  const float mean = s1 * (1.0f / 768.0f);
  const float var = fmaxf(s2 * (1.0f / 768.0f) - mean * mean, 0.0f);
  const float rs = 1.0f / (sqrtf(var) + 1e-5f);

  unsigned short* orow = (unsigned short*)out + (size_t)row * DD;
#pragma unroll
  for (int j = 0; j < 3; ++j) {
    const int c = (j * 64 + lane) * 4;
    float4 g4 = *(const float4*)(gain + c);
    float4 o4 = *(const float4*)(off + c);
    u16x4 pk;
    pk[0] = bf16bits(g4.x * ((v[j].x - mean) * rs) + o4.x);
    pk[1] = bf16bits(g4.y * ((v[j].y - mean) * rs) + o4.y);
    pk[2] = bf16bits(g4.z * ((v[j].z - mean) * rs) + o4.z);
    pk[3] = bf16bits(g4.w * ((v[j].w - mean) * rs) + o4.w);
    *(u16x4*)(orow + c) = pk;
  }
}

// ---------------- Transpose fp32 [R][C] -> bf16 [C][R] ----------------
__global__ __launch_bounds__(256) void transpose_generic(
    const float* __restrict__ in, __hip_bfloat16* __restrict__ out, int R, int C)
{
  __shared__ float tile[64][65];
  const int c0 = blockIdx.x * 64, r0 = blockIdx.y * 64;
  for (int i = threadIdx.x; i < 4096; i += 256) {
    int r = i >> 6, c = i & 63;
    tile[r][c] = in[(size_t)(r0 + r) * C + c0 + c];
  }
  __syncthreads();
  for (int i = threadIdx.x; i < 4096; i += 256) {
    int c = i >> 6, r = i & 63;
    out[(size_t)(c0 + c) * R + r0 + r] = __float2bfloat16(tile[r][c]);
  }
}

// Wq/Wk/Wv [H][D][DH] -> bf16 WqkvT [2304][768]
__global__ __launch_bounds__(256) void transpose_qkv(
    const float* __restrict__ Wq, const float* __restrict__ Wk,
    const float* __restrict__ Wv, __hip_bfloat16* __restrict__ out)
{
  __shared__ float tile[64][65];
  const int z = blockIdx.z;
  const int p = z / HH, h = z - p * HH;
  const float* in = (p == 0 ? Wq : (p == 1 ? Wk : Wv)) + (size_t)h * DD * DHH;
  const int r0 = blockIdx.y * 64;
  for (int i = threadIdx.x; i < 4096; i += 256) {
    int r = i >> 6, c = i & 63;
    tile[r][c] = in[(size_t)(r0 + r) * DHH + c];
  }
  __syncthreads();
  for (int i = threadIdx.x; i < 4096; i += 256) {
    int c = i >> 6, r = i & 63;
    out[(size_t)(p * DD + h * DHH + c) * DD + r0 + r] = __float2bfloat16(tile[r][c]);
  }
}

// ---------------- GEMM: bf16 A[M,K] x bf16 BT[N,K] ----------------
template<bool RELU, bool OUT_BF16, bool HAS_RES>
__global__ __launch_bounds__(256) void gemm_bt(
    const __hip_bfloat16* __restrict__ A, const __hip_bfloat16* __restrict__ BT,
    const float* __restrict__ bias, const float* __restrict__ res,
    void* __restrict__ outp, int M, int N, int K)
{
  __shared__ __hip_bfloat16 Alds[128 * 32];
  __shared__ __hip_bfloat16 Blds[128 * 32];
  const int tid = threadIdx.x;
  const int wave = tid >> 6;
  const int lane = tid & 63;
  const int fr = lane & 15, fq = lane >> 4;
  const int wr = wave >> 1, wc = wave & 1;
  const int bm = blockIdx.y * 128, bn = blockIdx.x * 128;

  const int srow = tid >> 2;
  const int scol = (tid & 3) * 8;
  const __hip_bfloat16* ag0 = A + (size_t)(bm + srow) * K + scol;
  const __hip_bfloat16* ag1 = A + (size_t)(bm + 64 + srow) * K + scol;
  const __hip_bfloat16* bg0 = BT + (size_t)(bn + srow) * K + scol;
  const __hip_bfloat16* bg1 = BT + (size_t)(bn + 64 + srow) * K + scol;
  __hip_bfloat16* la0 = Alds + wave * 512;
  __hip_bfloat16* la1 = Alds + 2048 + wave * 512;
  __hip_bfloat16* lb0 = Blds + wave * 512;
  __hip_bfloat16* lb1 = Blds + 2048 + wave * 512;

  f32x4 acc[4][4] = {};

  for (int k0 = 0; k0 < K; k0 += 32) {
    async_copy16(ag0 + k0, la0);
    async_copy16(ag1 + k0, la1);
    async_copy16(bg0 + k0, lb0);
    async_copy16(bg1 + k0, lb1);
    __syncthreads();
    bf16x8 af[4], bfr[4];
#pragma unroll
    for (int i = 0; i < 4; ++i)
      af[i] = *(const bf16x8*)(Alds + (wr * 64 + i * 16 + fr) * 32 + fq * 8);
#pragma unroll
    for (int j = 0; j < 4; ++j)
      bfr[j] = *(const bf16x8*)(Blds + (wc * 64 + j * 16 + fr) * 32 + fq * 8);
#pragma unroll
    for (int i = 0; i < 4; ++i)
#pragma unroll
      for (int j = 0; j < 4; ++j)
        acc[i][j] = __builtin_amdgcn_mfma_f32_16x16x32_bf16(af[i], bfr[j], acc[i][j], 0, 0, 0);
    __syncthreads();
  }

#pragma unroll
  for (int j = 0; j < 4; ++j) {
    const int c = bn + wc * 64 + j * 16 + fr;
    const float bv = bias[c];
#pragma unroll
    for (int i = 0; i < 4; ++i) {
#pragma unroll
      for (int r = 0; r < 4; ++r) {
        const int rr = bm + wr * 64 + i * 16 + fq * 4 + r;
        float v = acc[i][j][r] + bv;
        if (RELU) v = fmaxf(v, 0.0f);
        if (HAS_RES) v += res[(size_t)rr * N + c];
        if (OUT_BF16) ((__hip_bfloat16*)outp)[(size_t)rr * N + c] = __float2bfloat16(v);
        else          ((float*)outp)[(size_t)rr * N + c] = v;
      }
    }
  }
}

// ---------------- Split-K GEMM partial: fp32 partial, no bias ----------------
// grid (N/128, M/128, S); split z covers K range [z*K_per, (z+1)*K_per)
__global__ __launch_bounds__(256) void gemm_bt_sk(
    const __hip_bfloat16* __restrict__ A, const __hip_bfloat16* __restrict__ BT,
    float* __restrict__ part01, float* __restrict__ part23,
    int M, int N, int K, int K_per)
{
  __shared__ __hip_bfloat16 Alds[128 * 32];
  __shared__ __hip_bfloat16 Blds[128 * 32];
  const int tid = threadIdx.x;
  const int wave = tid >> 6;
  const int lane = tid & 63;
  const int fr = lane & 15, fq = lane >> 4;
  const int wr = wave >> 1, wc = wave & 1;
  const int bm = blockIdx.y * 128, bn = blockIdx.x * 128;
  const int z = blockIdx.z;
  float* part = (z < 2 ? part01 : part23) + (size_t)(z & 1) * M * N;
  const int kbase = z * K_per;

  const int srow = tid >> 2;
  const int scol = (tid & 3) * 8;
  const __hip_bfloat16* ag0 = A + (size_t)(bm + srow) * K + scol;
  const __hip_bfloat16* ag1 = A + (size_t)(bm + 64 + srow) * K + scol;
  const __hip_bfloat16* bg0 = BT + (size_t)(bn + srow) * K + scol;
  const __hip_bfloat16* bg1 = BT + (size_t)(bn + 64 + srow) * K + scol;
  __hip_bfloat16* la0 = Alds + wave * 512;
  __hip_bfloat16* la1 = Alds + 2048 + wave * 512;
  __hip_bfloat16* lb0 = Blds + wave * 512;
  __hip_bfloat16* lb1 = Blds + 2048 + wave * 512;

  f32x4 acc[4][4] = {};

  for (int k0 = kbase; k0 < kbase + K_per; k0 += 32) {
    async_copy16(ag0 + k0, la0);
    async_copy16(ag1 + k0, la1);
    async_copy16(bg0 + k0, lb0);
    async_copy16(bg1 + k0, lb1);
    __syncthreads();
    bf16x8 af[4], bfr[4];
#pragma unroll
    for (int i = 0; i < 4; ++i)
      af[i] = *(const bf16x8*)(Alds + (wr * 64 + i * 16 + fr) * 32 + fq * 8);
#pragma unroll
    for (int j = 0; j < 4; ++j)
      bfr[j] = *(const bf16x8*)(Blds + (wc * 64 + j * 16 + fr) * 32 + fq * 8);
#pragma unroll
    for (int i = 0; i < 4; ++i)
#pragma unroll
      for (int j = 0; j < 4; ++j)
        acc[i][j] = __builtin_amdgcn_mfma_f32_16x16x32_bf16(af[i], bfr[j], acc[i][j], 0, 0, 0);
    __syncthreads();
  }

#pragma unroll
  for (int j = 0; j < 4; ++j) {
    const int c = bn + wc * 64 + j * 16 + fr;
#pragma unroll
    for (int i = 0; i < 4; ++i) {
#pragma unroll
      for (int r = 0; r < 4; ++r) {
        const int rr = bm + wr * 64 + i * 16 + fq * 4 + r;
        part[(size_t)rr * N + c] = acc[i][j][r];
      }
    }
  }
}

// ---------------- combine 4 split-K partials + bias + residual -> fp32 ----------------
__global__ __launch_bounds__(256) void combine4(
    const float* __restrict__ part01, const float* __restrict__ part23,
    const float* __restrict__ res, const float* __restrict__ bias,
    float* __restrict__ out, int MN, int N)
{
  const int idx = (blockIdx.x * 256 + threadIdx.x) * 4;
  if (idx >= MN) return;
  const float4 a0 = *(const float4*)(part01 + idx);
  const float4 a1 = *(const float4*)(part01 + MN + idx);
  const float4 a2 = *(const float4*)(part23 + idx);
  const float4 a3 = *(const float4*)(part23 + MN + idx);
  const float4 rr = *(const float4*)(res + idx);
  const float4 bb = *(const float4*)(bias + (idx % N));
  float4 o;
  o.x = a0.x + a1.x + a2.x + a3.x + rr.x + bb.x;
  o.y = a0.y + a1.y + a2.y + a3.y + rr.y + bb.y;
  o.z = a0.z + a1.z + a2.z + a3.z + rr.z + bb.z;
  o.w = a0.w + a1.w + a2.w + a3.w + rr.w + bb.w;
  *(float4*)(out + idx) = o;
}

// ---------------- Flash attention, swapped-QK^T 32x32 ----------------
// 768 blocks x 512 threads (8 warps). XCD-aware decode: xcd = id&7 owns 3
// (b,h) heads -> per-XCD L2 working set ~2.3MB -> K/V fetched from HBM ~once.
// Block covers 64 q rows = two 32-row strips (warps 0-3 / 4-7) sharing the
// SAME KV tile set; within a strip warps split KV tiles mod 4 with private
// (m,l,O), LSE-combined via LDS at the end. BOTH K and V are cooperatively
// staged into XOR-swizzled LDS. launch_bounds(512,4): no spill.
__global__ __launch_bounds__(512, 4) void attn_kernel(
    const __hip_bfloat16* __restrict__ qkv, __hip_bfloat16* __restrict__ outp)
{
  const int HD = 3 * DD;   // 2304
  const int id = blockIdx.x;
  const int xcd = id & 7;
  const int j = id >> 3;              // 0..95 within XCD
  const int bh_l = j >> 5;            // 0..2
  const int c32 = j & 31;
  const int p = (bh_l == 0) ? (31 - c32)
              : (bh_l == 1) ? c32
                            : (31 - ((c32 + 16) & 31));
  const int bh = xcd * 3 + bh_l;      // 24 heads = 8 XCD x 3
  const int b = bh / HH, h = bh - (bh / HH) * HH;

  const int q0A = p * 64;             // block covers q in [q0A, q0A+64)
  const int tid = threadIdx.x, w = tid >> 6, lane = tid & 63;
  const int sidx = w >> 2;            // strip 0/1
  const int c = w & 3;                // kv-split index
  const int col = lane & 31, hi = lane >> 5;
  const int q0w = q0A + 32 * sidx;
  const int qg = q0w + col;

  const size_t base = (size_t)b * SS * HD;
  const __hip_bfloat16* Qp = qkv + base + h * DHH;
  const __hip_bfloat16* Kp = qkv + base + DD + h * DHH;
  const unsigned short* Vus = (const unsigned short*)(qkv + base + 2 * DD + h * DHH);

  __shared__ __align__(16) char sm[65536];
  char* const smV = sm;
  char* const smK = sm + 32768;

  bf16x8 qf[4];
#pragma unroll
  for (int kc = 0; kc < 4; ++kc)
    qf[kc] = *(const bf16x8*)(Qp + (size_t)qg * HD + kc * 16 + hi * 8);

  f32x16 o0 = {}, o1 = {};
  float mreg = -1e30f, lreg = 0.f;
  const float CS = 0.125f * 1.44269504f;

  const int sd = tid & 63;
  const int st8 = (tid >> 6) * 8;
  const int vswz = (sd * 128 + st8 * 2) ^ ((sd & 7) << 4);
  const int kr = tid >> 3;
  const int kd8 = (tid & 7) * 8;
  const int kswz = (kr * 128 + kd8 * 2) ^ ((kr & 7) << 4);

  const int ntiles = p + 1;
  const int nrounds = (ntiles + 3) >> 2;
  char* const vt_c = smV + c * 8192;
  char* const kt_c = smK + c * 8192;

  for (int jr = 0; jr < nrounds; ++jr) {
    __syncthreads();
#pragma unroll
    for (int tt = 0; tt < 4; ++tt) {
      const int tw = 4 * jr + tt;
      if (tw < ntiles) {
        const unsigned short* vrow = Vus + (size_t)(tw * 64 + st8) * HD + sd;
        union { unsigned short u[8]; bf16x8 v; } va;
#pragma unroll
        for (int e = 0; e < 8; ++e) va.u[e] = vrow[(size_t)e * HD];
        *(bf16x8*)(smV + tt * 8192 + vswz) = va.v;
        *(bf16x8*)(smK + tt * 8192 + kswz) =
            *(const bf16x8*)(Kp + (size_t)(tw * 64 + kr) * HD + kd8);
      }
    }
    __syncthreads();

    const int tw = 4 * jr + c;
    if (tw < ntiles) {
      const int kv0 = tw * 64;
      f32x16 s0 = {}, s1 = {};
#pragma unroll
      for (int kc = 0; kc < 4; ++kc) {
        const int koff2 = (kc * 16 + hi * 8) * 2;
        bf16x8 k0 = *(const bf16x8*)&kt_c[(col * 128 + koff2) ^ ((col & 7) << 4)];
        bf16x8 k1 = *(const bf16x8*)&kt_c[((32 + col) * 128 + koff2) ^ ((col & 7) << 4)];
        s0 = __builtin_amdgcn_mfma_f32_32x32x16_bf16(k0, qf[kc], s0, 0, 0, 0);
        s1 = __builtin_amdgcn_mfma_f32_32x32x16_bf16(k1, qf[kc], s1, 0, 0, 0);
      }
      if (kv0 + 63 > q0w) {
#pragma unroll
        for (int r = 0; r < 16; ++r) {
          const int tl = (r & 3) + 8 * (r >> 2) + 4 * hi;
          s0[r] = (kv0 + tl <= qg) ? s0[r] : -1e30f;
          s1[r] = (kv0 + 32 + tl <= qg) ? s1[r] : -1e30f;
        }
      }
      float mx = s0[0];
#pragma unroll
      for (int r = 1; r < 16; ++r) mx = fmaxf(mx, s0[r]);
#pragma unroll
      for (int r = 0; r < 16; ++r) mx = fmaxf(mx, s1[r]);
      mx = fmaxf(mx, __shfl_xor(mx, 32));
      const float mnew = fmaxf(mreg, mx);
      const float alpha = exp2f((mreg - mnew) * CS);
      mreg = mnew;
      const float mc = mnew * CS;
      float ps = 0.f;
#pragma unroll
      for (int r = 0; r < 16; ++r) {
        const float p0 = exp2f(s0[r] * CS - mc); s0[r] = p0; ps += p0;
        const float p1 = exp2f(s1[r] * CS - mc); s1[r] = p1; ps += p1;
      }
      ps += __shfl_xor(ps, 32);
      lreg = lreg * alpha + ps;
#pragma unroll
      for (int r = 0; r < 16; ++r) { o0[r] *= alpha; o1[r] *= alpha; }

      u32 pk0[4][2], pk1[4][2];
#pragma unroll
      for (int qd = 0; qd < 4; ++qd) {
        pk0[qd][0] = pack2(s0[4 * qd + 0], s0[4 * qd + 1]);
        pk0[qd][1] = pack2(s0[4 * qd + 2], s0[4 * qd + 3]);
        pk1[qd][0] = pack2(s1[4 * qd + 0], s1[4 * qd + 1]);
        pk1[qd][1] = pack2(s1[4 * qd + 2], s1[4 * qd + 3]);
      }
#pragma unroll
      for (int kc = 0; kc < 4; ++kc) {
        const int qa = 2 * (kc & 1), qb = qa + 1;
        const u32 A0 = (kc < 2) ? pk0[qa][0] : pk1[qa][0];
        const u32 A1 = (kc < 2) ? pk0[qa][1] : pk1[qa][1];
        const u32 B0 = (kc < 2) ? pk0[qb][0] : pk1[qb][0];
        const u32 B1 = (kc < 2) ? pk0[qb][1] : pk1[qb][1];
        const u32 send0 = hi ? A0 : B0;
        const u32 send1 = hi ? A1 : B1;
        const u32 recv0 = __shfl_xor(send0, 32);
        const u32 recv1 = __shfl_xor(send1, 32);
        const u32 su0 = hi ? B0 : A0;
        const u32 su1 = hi ? B1 : A1;
        union { u32 u[4]; bf16x8 v; } pf;
        pf.u[0] = hi ? recv0 : su0;
        pf.u[1] = hi ? recv1 : su1;
        pf.u[2] = hi ? su0 : recv0;
        pf.u[3] = hi ? su1 : recv1;
        const int toff2 = (kc * 16 + hi * 8) * 2;
        const int d0 = col, d1 = 32 + col;
        bf16x8 vfa = *(const bf16x8*)&vt_c[(d0 * 128 + toff2) ^ ((d0 & 7) << 4)];
        bf16x8 vfb = *(const bf16x8*)&vt_c[(d1 * 128 + toff2) ^ ((d1 & 7) << 4)];
        o0 = __builtin_amdgcn_mfma_f32_32x32x16_bf16(vfa, pf.v, o0, 0, 0, 0);
        o1 = __builtin_amdgcn_mfma_f32_32x32x16_bf16(vfb, pf.v, o1, 0, 0, 0);
      }
    }
  }

  // ---- combine the 4 kv-split partials per strip (two LDS phases) ----
  float* opart = (float*)sm;                 // [4][32][65]
  float* mlp   = (float*)(sm + 33280);       // [c][0][q]=m, [c][1][q]=l
#pragma unroll
  for (int s = 0; s < 2; ++s) {
    __syncthreads();
    if (sidx == s) {
#pragma unroll
      for (int r = 0; r < 16; ++r) {
        const int d = (r & 3) + 8 * (r >> 2) + 4 * hi;
        opart[(c * 32 + col) * 65 + d]      = o0[r];
        opart[(c * 32 + col) * 65 + d + 32] = o1[r];
      }
      if (hi == 0) {
        mlp[c * 64 + col]      = mreg;
        mlp[c * 64 + 32 + col] = lreg;
      }
    }
    __syncthreads();
    const int q = tid >> 4;            // 0..31
    const int d0 = (tid & 15) * 4;     // 0..60
    float mcv[4], lcv[4];
#pragma unroll
    for (int cc = 0; cc < 4; ++cc) {
      mcv[cc] = mlp[cc * 64 + q];
      lcv[cc] = mlp[cc * 64 + 32 + q];
    }
    float mstar = fmaxf(fmaxf(mcv[0], mcv[1]), fmaxf(mcv[2], mcv[3]));
    float av[4], lstar = 0.f;
#pragma unroll
    for (int cc = 0; cc < 4; ++cc) {
      av[cc] = exp2f((mcv[cc] - mstar) * CS);
      lstar += av[cc] * lcv[cc];
    }
    const float inv = 1.0f / lstar;
    float acc[4] = {};
#pragma unroll
    for (int cc = 0; cc < 4; ++cc) {
      const float a = av[cc];
#pragma unroll
      for (int e = 0; e < 4; ++e)
        acc[e] += a * opart[(cc * 32 + q) * 65 + d0 + e];
    }
    u16x4 w4;
#pragma unroll
    for (int e = 0; e < 4; ++e) w4[e] = bf16bits(acc[e] * inv);
    unsigned short* orow = (unsigned short*)outp +
        (size_t)(b * SS + q0A + 32 * s + q) * DD + h * DHH + d0;
    *(u16x4*)orow = w4;
  }
}

// ---------------- host ----------------
extern "C" void kernel_launch(void* const* d_in, const int* in_sizes, int n_in,
                              void* d_out, int out_size, void* d_ws, size_t ws_size,
                              hipStream_t stream)
{
  (void)in_sizes; (void)n_in; (void)out_size; (void)ws_size;
  const float* X  = (const float*)d_in[0];
  const float* Wq = (const float*)d_in[1];
  const float* bq = (const float*)d_in[2];
  const float* Wk = (const float*)d_in[3];
  const float* bk = (const float*)d_in[4];
  const float* Wv = (const float*)d_in[5];
  const float* bv = (const float*)d_in[6];
  const float* W0 = (const float*)d_in[7];
  const float* b0 = (const float*)d_in[8];
  const float* W1 = (const float*)d_in[9];
  const float* b1 = (const float*)d_in[10];
  const float* W2 = (const float*)d_in[11];
  const float* b2 = (const float*)d_in[12];
  const float* g1 = (const float*)d_in[13];
  const float* o1 = (const float*)d_in[14];
  const float* g2 = (const float*)d_in[15];
  const float* o2 = (const float*)d_in[16];

  char* ws = (char*)d_ws;
  auto alloc = [&](size_t bytes) {
    char* p = ws;
    ws += (bytes + 255) & ~(size_t)255;
    return p;
  };
  __hip_bfloat16* ln1    = (__hip_bfloat16*)alloc((size_t)MM * DD * 2);
  __hip_bfloat16* qkvb16 = (__hip_bfloat16*)alloc((size_t)MM * 3 * DD * 2);
  __hip_bfloat16* attnb  = (__hip_bfloat16*)alloc((size_t)MM * DD * 2);
  float*          hbuf   = (float*)alloc((size_t)MM * DD * 4);
  __hip_bfloat16* ln2    = (__hip_bfloat16*)alloc((size_t)MM * DD * 2);
  __hip_bfloat16* ffn1   = (__hip_bfloat16*)alloc((size_t)MM * DFF * 2);
  __hip_bfloat16* WqkvT  = (__hip_bfloat16*)alloc((size_t)3 * DD * DD * 2);
  __hip_bfloat16* W0T    = (__hip_bfloat16*)alloc((size_t)DD * DD * 2);
  __hip_bfloat16* W1T    = (__hip_bfloat16*)alloc((size_t)DFF * DD * 2);
  __hip_bfloat16* W2T    = (__hip_bfloat16*)alloc((size_t)DD * DFF * 2);
  float*          qkvbias= (float*)alloc((size_t)3 * DD * 4);
  float*          part23 = (float*)alloc((size_t)2 * MM * DD * 4);  // splits 2,3
  // splits 0,1 alias [ln1, qkvb16] (exactly 2*MM*DD*4 bytes, both dead by FFN2)
  float*          part01 = (float*)ln1;

  transpose_qkv<<<dim3(1, 12, 36), 256, 0, stream>>>(Wq, Wk, Wv, WqkvT);
  transpose_generic<<<dim3(12, 12), 256, 0, stream>>>(W0, W0T, DD, DD);
  transpose_generic<<<dim3(48, 12), 256, 0, stream>>>(W1, W1T, DD, DFF);
  transpose_generic<<<dim3(12, 48), 256, 0, stream>>>(W2, W2T, DFF, DD);
  hipMemcpyAsync(qkvbias,          bq, DD * 4, hipMemcpyDeviceToDevice, stream);
  hipMemcpyAsync(qkvbias + DD,     bk, DD * 4, hipMemcpyDeviceToDevice, stream);
  hipMemcpyAsync(qkvbias + 2 * DD, bv, DD * 4, hipMemcpyDeviceToDevice, stream);

  ln_kernel<<<MM / 4, 256, 0, stream>>>(X, g1, o1, ln1);
  gemm_bt<false, true, false><<<dim3(3 * DD / 128, MM / 128), 256, 0, stream>>>(
      ln1, WqkvT, qkvbias, nullptr, qkvb16, MM, 3 * DD, DD);
  attn_kernel<<<768, 512, 0, stream>>>(qkvb16, attnb);
  gemm_bt<false, false, true><<<dim3(DD / 128, MM / 128), 256, 0, stream>>>(
      attnb, W0T, b0, X, hbuf, MM, DD, DD);
  ln_kernel<<<MM / 4, 256, 0, stream>>>(hbuf, g2, o2, ln2);
  gemm_bt<true, true, false><<<dim3(DFF / 128, MM / 128), 256, 0, stream>>>(
      ln2, W1T, b1, nullptr, ffn1, MM, DFF, DD);
  // FFN2 via split-K=4: partials then combine(+bias+residual)
  gemm_bt_sk<<<dim3(DD / 128, MM / 128, 4), 256, 0, stream>>>(
      ffn1, W2T, part01, part23, MM, DD, DFF, DFF / 4);
  combine4<<<(MM * DD) / 1024, 256, 0, stream>>>(
      part01, part23, hbuf, b2, (float*)d_out, MM * DD, DD);
}

// Round 9
// 217.589 us; speedup vs baseline: 1.3974x; 1.0501x over previous
//
#include <hip/hip_runtime.h>
#include <hip/hip_bf16.h>
#include <cstdint>

// Problem constants
#define BB 2
#define SS 2048
#define DD 768
#define HH 12
#define DHH 64
#define DFF 3072
#define MM (BB * SS)   // 4096

typedef __attribute__((ext_vector_type(8))) short bf16x8;
typedef __attribute__((ext_vector_type(4))) float f32x4;
typedef __attribute__((ext_vector_type(16))) float f32x16;
typedef __attribute__((ext_vector_type(4))) unsigned short u16x4;
typedef __attribute__((ext_vector_type(8))) unsigned short u16x8;
typedef unsigned int u32;

#define DEV static __device__ __forceinline__

typedef __attribute__((address_space(1))) void AS1void;
typedef __attribute__((address_space(3))) void AS3void;

DEV void async_copy16(const void* g, void* l) {
  __builtin_amdgcn_global_load_lds((AS1void*)g, (AS3void*)l, 16, 0, 0);
}

DEV unsigned short bf16bits(float f) {
  __hip_bfloat16 h = __float2bfloat16(f);
  return *(unsigned short*)&h;
}

DEV u32 pack2(float a, float b) {
  return ((u32)bf16bits(b) << 16) | (u32)bf16bits(a);
}

// ---------------- LayerNorm: fp32 [rows][768] -> bf16 ----------------
__global__ __launch_bounds__(256) void ln_kernel(
    const float* __restrict__ x, const float* __restrict__ gain,
    const float* __restrict__ off, __hip_bfloat16* __restrict__ out)
{
  const int wave = threadIdx.x >> 6;
  const int lane = threadIdx.x & 63;
  const int row = blockIdx.x * 4 + wave;
  const float* xr = x + (size_t)row * DD;

  float4 v[3];
  float s1 = 0.f, s2 = 0.f;
#pragma unroll
  for (int j = 0; j < 3; ++j) {
    v[j] = *(const float4*)(xr + (j * 64 + lane) * 4);
    s1 += v[j].x + v[j].y + v[j].z + v[j].w;
    s2 += v[j].x * v[j].x + v[j].y * v[j].y + v[j].z * v[j].z + v[j].w * v[j].w;
  }
#pragma unroll
  for (int d = 1; d < 64; d <<= 1) {
    s1 += __shfl_xor(s1, d);
    s2 += __shfl_xor(s2, d);
  }
  const float mean = s1 * (1.0f / 768.0f);
  const float var = fmaxf(s2 * (1.0f / 768.0f) - mean * mean, 0.0f);
  const float rs = 1.0f / (sqrtf(var) + 1e-5f);

  unsigned short* orow = (unsigned short*)out + (size_t)row * DD;
#pragma unroll
  for (int j = 0; j < 3; ++j) {
    const int c = (j * 64 + lane) * 4;
    float4 g4 = *(const float4*)(gain + c);
    float4 o4 = *(const float4*)(off + c);
    u16x4 pk;
    pk[0] = bf16bits(g4.x * ((v[j].x - mean) * rs) + o4.x);
    pk[1] = bf16bits(g4.y * ((v[j].y - mean) * rs) + o4.y);
    pk[2] = bf16bits(g4.z * ((v[j].z - mean) * rs) + o4.z);
    pk[3] = bf16bits(g4.w * ((v[j].w - mean) * rs) + o4.w);
    *(u16x4*)(orow + c) = pk;
  }
}

// ---------------- Transpose fp32 [R][C] -> bf16 [C][R] ----------------
__global__ __launch_bounds__(256) void transpose_generic(
    const float* __restrict__ in, __hip_bfloat16* __restrict__ out, int R, int C)
{
  __shared__ float tile[64][65];
  const int c0 = blockIdx.x * 64, r0 = blockIdx.y * 64;
  for (int i = threadIdx.x; i < 4096; i += 256) {
    int r = i >> 6, c = i & 63;
    tile[r][c] = in[(size_t)(r0 + r) * C + c0 + c];
  }
  __syncthreads();
  for (int i = threadIdx.x; i < 4096; i += 256) {
    int c = i >> 6, r = i & 63;
    out[(size_t)(c0 + c) * R + r0 + r] = __float2bfloat16(tile[r][c]);
  }
}

// Wq/Wk/Wv [H][D][DH] -> bf16 WqkvT [2304][768]
__global__ __launch_bounds__(256) void transpose_qkv(
    const float* __restrict__ Wq, const float* __restrict__ Wk,
    const float* __restrict__ Wv, __hip_bfloat16* __restrict__ out)
{
  __shared__ float tile[64][65];
  const int z = blockIdx.z;
  const int p = z / HH, h = z - p * HH;
  const float* in = (p == 0 ? Wq : (p == 1 ? Wk : Wv)) + (size_t)h * DD * DHH;
  const int r0 = blockIdx.y * 64;
  for (int i = threadIdx.x; i < 4096; i += 256) {
    int r = i >> 6, c = i & 63;
    tile[r][c] = in[(size_t)(r0 + r) * DHH + c];
  }
  __syncthreads();
  for (int i = threadIdx.x; i < 4096; i += 256) {
    int c = i >> 6, r = i & 63;
    out[(size_t)(p * DD + h * DHH + c) * DD + r0 + r] = __float2bfloat16(tile[r][c]);
  }
}

// ---------------- GEMM: bf16 A[M,K] x bf16 BT[N,K], 2-phase dbuf ----------------
template<bool RELU, bool OUT_BF16, bool HAS_RES>
__global__ __launch_bounds__(256) void gemm_bt(
    const __hip_bfloat16* __restrict__ A, const __hip_bfloat16* __restrict__ BT,
    const float* __restrict__ bias, const float* __restrict__ res,
    void* __restrict__ outp, int M, int N, int K)
{
  __shared__ __hip_bfloat16 Alds[2][128 * 32];
  __shared__ __hip_bfloat16 Blds[2][128 * 32];
  const int tid = threadIdx.x;
  const int wave = tid >> 6;
  const int lane = tid & 63;
  const int fr = lane & 15, fq = lane >> 4;
  const int wr = wave >> 1, wc = wave & 1;
  const int bm = blockIdx.y * 128, bn = blockIdx.x * 128;

  const int srow = tid >> 2;
  const int scol = (tid & 3) * 8;
  const __hip_bfloat16* ag0 = A + (size_t)(bm + srow) * K + scol;
  const __hip_bfloat16* ag1 = A + (size_t)(bm + 64 + srow) * K + scol;
  const __hip_bfloat16* bg0 = BT + (size_t)(bn + srow) * K + scol;
  const __hip_bfloat16* bg1 = BT + (size_t)(bn + 64 + srow) * K + scol;
  const int so = wave * 512;

  f32x4 acc[4][4] = {};

  async_copy16(ag0, &Alds[0][so]);
  async_copy16(ag1, &Alds[0][2048 + so]);
  async_copy16(bg0, &Blds[0][so]);
  async_copy16(bg1, &Blds[0][2048 + so]);
  __syncthreads();

  const int niter = K / 32;
  for (int i = 0; i < niter; ++i) {
    const int cur = i & 1;
    if (i + 1 < niter) {
      const int k1 = (i + 1) * 32;
      async_copy16(ag0 + k1, &Alds[cur ^ 1][so]);
      async_copy16(ag1 + k1, &Alds[cur ^ 1][2048 + so]);
      async_copy16(bg0 + k1, &Blds[cur ^ 1][so]);
      async_copy16(bg1 + k1, &Blds[cur ^ 1][2048 + so]);
    }
    bf16x8 af[4], bfr[4];
#pragma unroll
    for (int i4 = 0; i4 < 4; ++i4)
      af[i4] = *(const bf16x8*)(&Alds[cur][(wr * 64 + i4 * 16 + fr) * 32 + fq * 8]);
#pragma unroll
    for (int j4 = 0; j4 < 4; ++j4)
      bfr[j4] = *(const bf16x8*)(&Blds[cur][(wc * 64 + j4 * 16 + fr) * 32 + fq * 8]);
#pragma unroll
    for (int i4 = 0; i4 < 4; ++i4)
#pragma unroll
      for (int j4 = 0; j4 < 4; ++j4)
        acc[i4][j4] = __builtin_amdgcn_mfma_f32_16x16x32_bf16(af[i4], bfr[j4], acc[i4][j4], 0, 0, 0);
    __syncthreads();
  }

#pragma unroll
  for (int j = 0; j < 4; ++j) {
    const int c = bn + wc * 64 + j * 16 + fr;
    const float bv = bias[c];
#pragma unroll
    for (int i = 0; i < 4; ++i) {
#pragma unroll
      for (int r = 0; r < 4; ++r) {
        const int rr = bm + wr * 64 + i * 16 + fq * 4 + r;
        float v = acc[i][j][r] + bv;
        if (RELU) v = fmaxf(v, 0.0f);
        if (HAS_RES) v += res[(size_t)rr * N + c];
        if (OUT_BF16) ((__hip_bfloat16*)outp)[(size_t)rr * N + c] = __float2bfloat16(v);
        else          ((float*)outp)[(size_t)rr * N + c] = v;
      }
    }
  }
}

// ---------------- Split-K GEMM partial (2-phase dbuf): fp32 partial ----------------
__global__ __launch_bounds__(256) void gemm_bt_sk(
    const __hip_bfloat16* __restrict__ A, const __hip_bfloat16* __restrict__ BT,
    float* __restrict__ part01, float* __restrict__ part23,
    int M, int N, int K, int K_per)
{
  __shared__ __hip_bfloat16 Alds[2][128 * 32];
  __shared__ __hip_bfloat16 Blds[2][128 * 32];
  const int tid = threadIdx.x;
  const int wave = tid >> 6;
  const int lane = tid & 63;
  const int fr = lane & 15, fq = lane >> 4;
  const int wr = wave >> 1, wc = wave & 1;
  const int bm = blockIdx.y * 128, bn = blockIdx.x * 128;
  const int z = blockIdx.z;
  float* part = (z < 2 ? part01 : part23) + (size_t)(z & 1) * M * N;
  const int kbase = z * K_per;

  const int srow = tid >> 2;
  const int scol = (tid & 3) * 8;
  const __hip_bfloat16* ag0 = A + (size_t)(bm + srow) * K + scol + kbase;
  const __hip_bfloat16* ag1 = A + (size_t)(bm + 64 + srow) * K + scol + kbase;
  const __hip_bfloat16* bg0 = BT + (size_t)(bn + srow) * K + scol + kbase;
  const __hip_bfloat16* bg1 = BT + (size_t)(bn + 64 + srow) * K + scol + kbase;
  const int so = wave * 512;

  f32x4 acc[4][4] = {};

  async_copy16(ag0, &Alds[0][so]);
  async_copy16(ag1, &Alds[0][2048 + so]);
  async_copy16(bg0, &Blds[0][so]);
  async_copy16(bg1, &Blds[0][2048 + so]);
  __syncthreads();

  const int niter = K_per / 32;
  for (int i = 0; i < niter; ++i) {
    const int cur = i & 1;
    if (i + 1 < niter) {
      const int k1 = (i + 1) * 32;
      async_copy16(ag0 + k1, &Alds[cur ^ 1][so]);
      async_copy16(ag1 + k1, &Alds[cur ^ 1][2048 + so]);
      async_copy16(bg0 + k1, &Blds[cur ^ 1][so]);
      async_copy16(bg1 + k1, &Blds[cur ^ 1][2048 + so]);
    }
    bf16x8 af[4], bfr[4];
#pragma unroll
    for (int i4 = 0; i4 < 4; ++i4)
      af[i4] = *(const bf16x8*)(&Alds[cur][(wr * 64 + i4 * 16 + fr) * 32 + fq * 8]);
#pragma unroll
    for (int j4 = 0; j4 < 4; ++j4)
      bfr[j4] = *(const bf16x8*)(&Blds[cur][(wc * 64 + j4 * 16 + fr) * 32 + fq * 8]);
#pragma unroll
    for (int i4 = 0; i4 < 4; ++i4)
#pragma unroll
      for (int j4 = 0; j4 < 4; ++j4)
        acc[i4][j4] = __builtin_amdgcn_mfma_f32_16x16x32_bf16(af[i4], bfr[j4], acc[i4][j4], 0, 0, 0);
    __syncthreads();
  }

#pragma unroll
  for (int j = 0; j < 4; ++j) {
    const int c = bn + wc * 64 + j * 16 + fr;
#pragma unroll
    for (int i = 0; i < 4; ++i) {
#pragma unroll
      for (int r = 0; r < 4; ++r) {
        const int rr = bm + wr * 64 + i * 16 + fq * 4 + r;
        part[(size_t)rr * N + c] = acc[i][j][r];
      }
    }
  }
}

// ---------------- combine 4 split-K partials + bias + residual -> fp32 ----------------
__global__ __launch_bounds__(256) void combine4(
    const float* __restrict__ part01, const float* __restrict__ part23,
    const float* __restrict__ res, const float* __restrict__ bias,
    float* __restrict__ out, int MN, int N)
{
  const int idx = (blockIdx.x * 256 + threadIdx.x) * 4;
  if (idx >= MN) return;
  const float4 a0 = *(const float4*)(part01 + idx);
  const float4 a1 = *(const float4*)(part01 + MN + idx);
  const float4 a2 = *(const float4*)(part23 + idx);
  const float4 a3 = *(const float4*)(part23 + MN + idx);
  const float4 rr = *(const float4*)(res + idx);
  const float4 bb = *(const float4*)(bias + (idx % N));
  float4 o;
  o.x = a0.x + a1.x + a2.x + a3.x + rr.x + bb.x;
  o.y = a0.y + a1.y + a2.y + a3.y + rr.y + bb.y;
  o.z = a0.z + a1.z + a2.z + a3.z + rr.z + bb.z;
  o.w = a0.w + a1.w + a2.w + a3.w + rr.w + bb.w;
  *(float4*)(out + idx) = o;
}

// ---------------- Flash attention, swapped-QK^T 32x32 ----------------
// 768 blocks x 256 threads (4 warps). XCD decode: xcd=id&7 owns 3 heads;
// q-block p (0..31) covers 64 q rows = TWO 32-row strips (warp pairs).
// Within a strip the 2 warps split KV tiles mod 2 with private (m,l,O),
// LSE-combined via LDS. Both strips need exactly p+1 tiles (block-uniform).
// 2 tiles staged/round (K+V, XOR-swizzled) -> LDS 32KB -> 4-5 blocks/CU.
__global__ __launch_bounds__(256, 4) void attn_kernel(
    const __hip_bfloat16* __restrict__ qkv, __hip_bfloat16* __restrict__ outp)
{
  const int HD = 3 * DD;   // 2304
  const int id = blockIdx.x;
  const int xcd = id & 7;
  const int j = id >> 3;              // 0..95 within XCD
  const int bh_l = j >> 5;            // 0..2
  const int c32 = j & 31;             // q-block within head, 0..31
  const int p = (bh_l == 0) ? (31 - c32)
              : (bh_l == 1) ? c32
                            : (31 - ((c32 + 16) & 31));
  const int bh = xcd * 3 + bh_l;      // 24 heads = 8 XCD x 3
  const int b = bh / HH, h = bh - (bh / HH) * HH;

  const int q0A = p * 64;             // block covers q in [q0A, q0A+64)
  const int tid = threadIdx.x, w = tid >> 6, lane = tid & 63;
  const int sidx = w >> 1;            // strip 0/1
  const int c = w & 1;                // kv-split index 0/1
  const int col = lane & 31, hi = lane >> 5;
  const int q0w = q0A + 32 * sidx;
  const int qg = q0w + col;

  const size_t base = (size_t)b * SS * HD;
  const __hip_bfloat16* Qp = qkv + base + h * DHH;
  const __hip_bfloat16* Kp = qkv + base + DD + h * DHH;
  const unsigned short* Vus = (const unsigned short*)(qkv + base + 2 * DD + h * DHH);

  // LDS: 2 x 8KB swizzled Vt + 2 x 8KB swizzled K = 32KB.
  // Epilogue reuses [0,17152): opart[2][32][65] f32 + ml[2][2][32] f32.
  __shared__ __align__(16) char sm[32768];
  char* const smV = sm;
  char* const smK = sm + 16384;

  bf16x8 qf[4];
#pragma unroll
  for (int kc = 0; kc < 4; ++kc)
    qf[kc] = *(const bf16x8*)(Qp + (size_t)qg * HD + kc * 16 + hi * 8);

  f32x16 o0 = {}, o1 = {};
  float mreg = -1e30f, lreg = 0.f;
  const float CS = 0.125f * 1.44269504f;

  // staging: 256 threads cover 2 tiles, 2 chunks each
  const int sd = tid & 63;
  const int stq = (tid >> 6) * 8;               // V t-rows {0,8,16,24} (+32)
  const int vswz0 = (sd * 128 + stq * 2) ^ ((sd & 7) << 4);
  const int vswz1 = (sd * 128 + (stq + 32) * 2) ^ ((sd & 7) << 4);
  const int kr = tid >> 3;                      // K rows 0..31 (+32)
  const int kd8 = (tid & 7) * 8;
  const int kswz0 = (kr * 128 + kd8 * 2) ^ ((kr & 7) << 4);
  const int kswz1 = kswz0 + 32 * 128;           // (kr+32)&7 == kr&7

  const int ntiles = p + 1;                     // same for both strips
  const int nrounds = (ntiles + 1) >> 1;
  char* const vt_c = smV + c * 8192;
  char* const kt_c = smK + c * 8192;

  for (int jr = 0; jr < nrounds; ++jr) {
    __syncthreads();
#pragma unroll
    for (int tt = 0; tt < 2; ++tt) {
      const int tw = 2 * jr + tt;
      if (tw < ntiles) {
        const unsigned short* vrow = Vus + (size_t)(tw * 64 + stq) * HD + sd;
        union { unsigned short u[8]; bf16x8 v; } va, vb;
#pragma unroll
        for (int e = 0; e < 8; ++e) va.u[e] = vrow[(size_t)e * HD];
#pragma unroll
        for (int e = 0; e < 8; ++e) vb.u[e] = vrow[(size_t)(32 + e) * HD];
        *(bf16x8*)(smV + tt * 8192 + vswz0) = va.v;
        *(bf16x8*)(smV + tt * 8192 + vswz1) = vb.v;
        *(bf16x8*)(smK + tt * 8192 + kswz0) =
            *(const bf16x8*)(Kp + (size_t)(tw * 64 + kr) * HD + kd8);
        *(bf16x8*)(smK + tt * 8192 + kswz1) =
            *(const bf16x8*)(Kp + (size_t)(tw * 64 + 32 + kr) * HD + kd8);
      }
    }
    __syncthreads();

    const int tw = 2 * jr + c;
    if (tw < ntiles) {
      const int kv0 = tw * 64;
      f32x16 s0 = {}, s1 = {};
#pragma unroll
      for (int kc = 0; kc < 4; ++kc) {
        const int koff2 = (kc * 16 + hi * 8) * 2;
        bf16x8 k0 = *(const bf16x8*)&kt_c[(col * 128 + koff2) ^ ((col & 7) << 4)];
        bf16x8 k1 = *(const bf16x8*)&kt_c[((32 + col) * 128 + koff2) ^ ((col & 7) << 4)];
        s0 = __builtin_amdgcn_mfma_f32_32x32x16_bf16(k0, qf[kc], s0, 0, 0, 0);
        s1 = __builtin_amdgcn_mfma_f32_32x32x16_bf16(k1, qf[kc], s1, 0, 0, 0);
      }
      if (kv0 + 63 > q0w) {
#pragma unroll
        for (int r = 0; r < 16; ++r) {
          const int tl = (r & 3) + 8 * (r >> 2) + 4 * hi;
          s0[r] = (kv0 + tl <= qg) ? s0[r] : -1e30f;
          s1[r] = (kv0 + 32 + tl <= qg) ? s1[r] : -1e30f;
        }
      }
      float mx = s0[0];
#pragma unroll
      for (int r = 1; r < 16; ++r) mx = fmaxf(mx, s0[r]);
#pragma unroll
      for (int r = 0; r < 16; ++r) mx = fmaxf(mx, s1[r]);
      mx = fmaxf(mx, __shfl_xor(mx, 32));
      const float mnew = fmaxf(mreg, mx);
      const float alpha = exp2f((mreg - mnew) * CS);
      mreg = mnew;
      const float mc = mnew * CS;
      float ps = 0.f;
#pragma unroll
      for (int r = 0; r < 16; ++r) {
        const float p0 = exp2f(s0[r] * CS - mc); s0[r] = p0; ps += p0;
        const float p1 = exp2f(s1[r] * CS - mc); s1[r] = p1; ps += p1;
      }
      ps += __shfl_xor(ps, 32);
      lreg = lreg * alpha + ps;
#pragma unroll
      for (int r = 0; r < 16; ++r) { o0[r] *= alpha; o1[r] *= alpha; }

      u32 pk0[4][2], pk1[4][2];
#pragma unroll
      for (int qd = 0; qd < 4; ++qd) {
        pk0[qd][0] = pack2(s0[4 * qd + 0], s0[4 * qd + 1]);
        pk0[qd][1] = pack2(s0[4 * qd + 2], s0[4 * qd + 3]);
        pk1[qd][0] = pack2(s1[4 * qd + 0], s1[4 * qd + 1]);
        pk1[qd][1] = pack2(s1[4 * qd + 2], s1[4 * qd + 3]);
      }
#pragma unroll
      for (int kc = 0; kc < 4; ++kc) {
        const int qa = 2 * (kc & 1), qb = qa + 1;
        const u32 A0 = (kc < 2) ? pk0[qa][0] : pk1[qa][0];
        const u32 A1 = (kc < 2) ? pk0[qa][1] : pk1[qa][1];
        const u32 B0 = (kc < 2) ? pk0[qb][0] : pk1[qb][0];
        const u32 B1 = (kc < 2) ? pk0[qb][1] : pk1[qb][1];
        const u32 send0 = hi ? A0 : B0;
        const u32 send1 = hi ? A1 : B1;
        const u32 recv0 = __shfl_xor(send0, 32);
        const u32 recv1 = __shfl_xor(send1, 32);
        const u32 su0 = hi ? B0 : A0;
        const u32 su1 = hi ? B1 : A1;
        union { u32 u[4]; bf16x8 v; } pf;
        pf.u[0] = hi ? recv0 : su0;
        pf.u[1] = hi ? recv1 : su1;
        pf.u[2] = hi ? su0 : recv0;
        pf.u[3] = hi ? su1 : recv1;
        const int toff2 = (kc * 16 + hi * 8) * 2;
        const int d0 = col, d1 = 32 + col;
        bf16x8 vfa = *(const bf16x8*)&vt_c[(d0 * 128 + toff2) ^ ((d0 & 7) << 4)];
        bf16x8 vfb = *(const bf16x8*)&vt_c[(d1 * 128 + toff2) ^ ((d1 & 7) << 4)];
        o0 = __builtin_amdgcn_mfma_f32_32x32x16_bf16(vfa, pf.v, o0, 0, 0, 0);
        o1 = __builtin_amdgcn_mfma_f32_32x32x16_bf16(vfb, pf.v, o1, 0, 0, 0);
      }
    }
  }

  // ---- combine the 2 kv-split partials per strip (2 LDS phases) ----
  float* opart = (float*)sm;                 // [2][32][65]
  float* mlp   = (float*)(sm + 16640);       // [c][0][q]=m, [c][1][q]=l
#pragma unroll
  for (int s = 0; s < 2; ++s) {
    __syncthreads();
    if (sidx == s) {
#pragma unroll
      for (int r = 0; r < 16; ++r) {
        const int d = (r & 3) + 8 * (r >> 2) + 4 * hi;
        opart[(c * 32 + col) * 65 + d]      = o0[r];
        opart[(c * 32 + col) * 65 + d + 32] = o1[r];
      }
      if (hi == 0) {
        mlp[c * 64 + col]      = mreg;
        mlp[c * 64 + 32 + col] = lreg;
      }
    }
    __syncthreads();
    const int q = tid >> 3;            // 0..31
    const int d0 = (tid & 7) * 8;      // 0..56
    float mcv[2], lcv[2];
#pragma unroll
    for (int cc = 0; cc < 2; ++cc) {
      mcv[cc] = mlp[cc * 64 + q];
      lcv[cc] = mlp[cc * 64 + 32 + q];
    }
    const float mstar = fmaxf(mcv[0], mcv[1]);
    float av[2], lstar = 0.f;
#pragma unroll
    for (int cc = 0; cc < 2; ++cc) {
      av[cc] = exp2f((mcv[cc] - mstar) * CS);
      lstar += av[cc] * lcv[cc];
    }
    const float inv = 1.0f / lstar;
    float acc[8] = {};
#pragma unroll
    for (int cc = 0; cc < 2; ++cc) {
      const float a = av[cc];
#pragma unroll
      for (int e = 0; e < 8; ++e)
        acc[e] += a * opart[(cc * 32 + q) * 65 + d0 + e];
    }
    u16x8 w8;
#pragma unroll
    for (int e = 0; e < 8; ++e) w8[e] = bf16bits(acc[e] * inv);
    unsigned short* orow = (unsigned short*)outp +
        (size_t)(b * SS + q0A + 32 * s + q) * DD + h * DHH + d0;
    *(u16x8*)orow = w8;
  }
}

// ---------------- host ----------------
extern "C" void kernel_launch(void* const* d_in, const int* in_sizes, int n_in,
                              void* d_out, int out_size, void* d_ws, size_t ws_size,
                              hipStream_t stream)
{
  (void)in_sizes; (void)n_in; (void)out_size; (void)ws_size;
  const float* X  = (const float*)d_in[0];
  const float* Wq = (const float*)d_in[1];
  const float* bq = (const float*)d_in[2];
  const float* Wk = (const float*)d_in[3];
  const float* bk = (const float*)d_in[4];
  const float* Wv = (const float*)d_in[5];
  const float* bv = (const float*)d_in[6];
  const float* W0 = (const float*)d_in[7];
  const float* b0 = (const float*)d_in[8];
  const float* W1 = (const float*)d_in[9];
  const float* b1 = (const float*)d_in[10];
  const float* W2 = (const float*)d_in[11];
  const float* b2 = (const float*)d_in[12];
  const float* g1 = (const float*)d_in[13];
  const float* o1 = (const float*)d_in[14];
  const float* g2 = (const float*)d_in[15];
  const float* o2 = (const float*)d_in[16];

  char* ws = (char*)d_ws;
  auto alloc = [&](size_t bytes) {
    char* p = ws;
    ws += (bytes + 255) & ~(size_t)255;
    return p;
  };
  __hip_bfloat16* ln1    = (__hip_bfloat16*)alloc((size_t)MM * DD * 2);
  __hip_bfloat16* qkvb16 = (__hip_bfloat16*)alloc((size_t)MM * 3 * DD * 2);
  __hip_bfloat16* attnb  = (__hip_bfloat16*)alloc((size_t)MM * DD * 2);
  float*          hbuf   = (float*)alloc((size_t)MM * DD * 4);
  __hip_bfloat16* ln2    = (__hip_bfloat16*)alloc((size_t)MM * DD * 2);
  __hip_bfloat16* ffn1   = (__hip_bfloat16*)alloc((size_t)MM * DFF * 2);
  __hip_bfloat16* WqkvT  = (__hip_bfloat16*)alloc((size_t)3 * DD * DD * 2);
  __hip_bfloat16* W0T    = (__hip_bfloat16*)alloc((size_t)DD * DD * 2);
  __hip_bfloat16* W1T    = (__hip_bfloat16*)alloc((size_t)DFF * DD * 2);
  __hip_bfloat16* W2T    = (__hip_bfloat16*)alloc((size_t)DD * DFF * 2);
  float*          qkvbias= (float*)alloc((size_t)3 * DD * 4);
  float*          part23 = (float*)alloc((size_t)2 * MM * DD * 4);  // splits 2,3
  // splits 0,1 alias [ln1, qkvb16] (exactly 2*MM*DD*4 bytes, both dead by FFN2)
  float*          part01 = (float*)ln1;

  transpose_qkv<<<dim3(1, 12, 36), 256, 0, stream>>>(Wq, Wk, Wv, WqkvT);
  transpose_generic<<<dim3(12, 12), 256, 0, stream>>>(W0, W0T, DD, DD);
  transpose_generic<<<dim3(48, 12), 256, 0, stream>>>(W1, W1T, DD, DFF);
  transpose_generic<<<dim3(12, 48), 256, 0, stream>>>(W2, W2T, DFF, DD);
  hipMemcpyAsync(qkvbias,          bq, DD * 4, hipMemcpyDeviceToDevice, stream);
  hipMemcpyAsync(qkvbias + DD,     bk, DD * 4, hipMemcpyDeviceToDevice, stream);
  hipMemcpyAsync(qkvbias + 2 * DD, bv, DD * 4, hipMemcpyDeviceToDevice, stream);

  ln_kernel<<<MM / 4, 256, 0, stream>>>(X, g1, o1, ln1);
  gemm_bt<false, true, false><<<dim3(3 * DD / 128, MM / 128), 256, 0, stream>>>(
      ln1, WqkvT, qkvbias, nullptr, qkvb16, MM, 3 * DD, DD);
  attn_kernel<<<768, 256, 0, stream>>>(qkvb16, attnb);
  gemm_bt<false, false, true><<<dim3(DD / 128, MM / 128), 256, 0, stream>>>(
      attnb, W0T, b0, X, hbuf, MM, DD, DD);
  ln_kernel<<<MM / 4, 256, 0, stream>>>(hbuf, g2, o2, ln2);
  gemm_bt<true, true, false><<<dim3(DFF / 128, MM / 128), 256, 0, stream>>>(
      ln2, W1T, b1, nullptr, ffn1, MM, DFF, DD);
  // FFN2 via split-K=4: partials then combine(+bias+residual)
  gemm_bt_sk<<<dim3(DD / 128, MM / 128, 4), 256, 0, stream>>>(
      ffn1, W2T, part01, part23, MM, DD, DFF, DFF / 4);
  combine4<<<(MM * DD) / 1024, 256, 0, stream>>>(
      part01, part23, hbuf, b2, (float*)d_out, MM * DD, DD);
}

// Round 10
// 216.187 us; speedup vs baseline: 1.4064x; 1.0065x over previous
//
#include <hip/hip_runtime.h>
#include <hip/hip_bf16.h>
#include <cstdint>

// Problem constants
#define BB 2
#define SS 2048
#define DD 768
#define HH 12
#define DHH 64
#define DFF 3072
#define MM (BB * SS)   // 4096

typedef __attribute__((ext_vector_type(8))) short bf16x8;
typedef __attribute__((ext_vector_type(4))) float f32x4;
typedef __attribute__((ext_vector_type(16))) float f32x16;
typedef __attribute__((ext_vector_type(4))) unsigned short u16x4;
typedef __attribute__((ext_vector_type(8))) unsigned short u16x8;
typedef unsigned int u32;

#define DEV static __device__ __forceinline__

typedef __attribute__((address_space(1))) void AS1void;
typedef __attribute__((address_space(3))) void AS3void;

DEV void async_copy16(const void* g, void* l) {
  __builtin_amdgcn_global_load_lds((AS1void*)g, (AS3void*)l, 16, 0, 0);
}

DEV unsigned short bf16bits(float f) {
  __hip_bfloat16 h = __float2bfloat16(f);
  return *(unsigned short*)&h;
}

DEV u32 pack2(float a, float b) {
  return ((u32)bf16bits(b) << 16) | (u32)bf16bits(a);
}

// ---------------- LayerNorm: fp32 [rows][768] -> bf16 ----------------
__global__ __launch_bounds__(256) void ln_kernel(
    const float* __restrict__ x, const float* __restrict__ gain,
    const float* __restrict__ off, __hip_bfloat16* __restrict__ out)
{
  const int wave = threadIdx.x >> 6;
  const int lane = threadIdx.x & 63;
  const int row = blockIdx.x * 4 + wave;
  const float* xr = x + (size_t)row * DD;

  float4 v[3];
  float s1 = 0.f, s2 = 0.f;
#pragma unroll
  for (int j = 0; j < 3; ++j) {
    v[j] = *(const float4*)(xr + (j * 64 + lane) * 4);
    s1 += v[j].x + v[j].y + v[j].z + v[j].w;
    s2 += v[j].x * v[j].x + v[j].y * v[j].y + v[j].z * v[j].z + v[j].w * v[j].w;
  }
#pragma unroll
  for (int d = 1; d < 64; d <<= 1) {
    s1 += __shfl_xor(s1, d);
    s2 += __shfl_xor(s2, d);
  }
  const float mean = s1 * (1.0f / 768.0f);
  const float var = fmaxf(s2 * (1.0f / 768.0f) - mean * mean, 0.0f);
  const float rs = 1.0f / (sqrtf(var) + 1e-5f);

  unsigned short* orow = (unsigned short*)out + (size_t)row * DD;
#pragma unroll
  for (int j = 0; j < 3; ++j) {
    const int c = (j * 64 + lane) * 4;
    float4 g4 = *(const float4*)(gain + c);
    float4 o4 = *(const float4*)(off + c);
    u16x4 pk;
    pk[0] = bf16bits(g4.x * ((v[j].x - mean) * rs) + o4.x);
    pk[1] = bf16bits(g4.y * ((v[j].y - mean) * rs) + o4.y);
    pk[2] = bf16bits(g4.z * ((v[j].z - mean) * rs) + o4.z);
    pk[3] = bf16bits(g4.w * ((v[j].w - mean) * rs) + o4.w);
    *(u16x4*)(orow + c) = pk;
  }
}

// ---------------- Transpose fp32 [R][C] -> bf16 [C][R] ----------------
__global__ __launch_bounds__(256) void transpose_generic(
    const float* __restrict__ in, __hip_bfloat16* __restrict__ out, int R, int C)
{
  __shared__ float tile[64][65];
  const int c0 = blockIdx.x * 64, r0 = blockIdx.y * 64;
  for (int i = threadIdx.x; i < 4096; i += 256) {
    int r = i >> 6, c = i & 63;
    tile[r][c] = in[(size_t)(r0 + r) * C + c0 + c];
  }
  __syncthreads();
  for (int i = threadIdx.x; i < 4096; i += 256) {
    int c = i >> 6, r = i & 63;
    out[(size_t)(c0 + c) * R + r0 + r] = __float2bfloat16(tile[r][c]);
  }
}

// Wq/Wk/Wv [H][D][DH] -> bf16 WqkvT [2304][768]
__global__ __launch_bounds__(256) void transpose_qkv(
    const float* __restrict__ Wq, const float* __restrict__ Wk,
    const float* __restrict__ Wv, __hip_bfloat16* __restrict__ out)
{
  __shared__ float tile[64][65];
  const int z = blockIdx.z;
  const int p = z / HH, h = z - p * HH;
  const float* in = (p == 0 ? Wq : (p == 1 ? Wk : Wv)) + (size_t)h * DD * DHH;
  const int r0 = blockIdx.y * 64;
  for (int i = threadIdx.x; i < 4096; i += 256) {
    int r = i >> 6, c = i & 63;
    tile[r][c] = in[(size_t)(r0 + r) * DHH + c];
  }
  __syncthreads();
  for (int i = threadIdx.x; i < 4096; i += 256) {
    int c = i >> 6, r = i & 63;
    out[(size_t)(p * DD + h * DHH + c) * DD + r0 + r] = __float2bfloat16(tile[r][c]);
  }
}

// ---------------- V transpose: qkv [M][2304] V-part -> VT [b*H+h][64][2048] ----------------
// grid (S/64, B*H); one 64x64 tile per block.
__global__ __launch_bounds__(256) void vtrans_kernel(
    const __hip_bfloat16* __restrict__ qkv, __hip_bfloat16* __restrict__ vt)
{
  __shared__ unsigned short tile[64][65];
  const int bh = blockIdx.y;
  const int b = bh / HH, h = bh - (bh / HH) * HH;
  const int t0 = blockIdx.x * 64;
  const unsigned short* src = (const unsigned short*)qkv
      + (size_t)(b * SS) * (3 * DD) + 2 * DD + h * DHH;
  for (int i = threadIdx.x; i < 4096; i += 256) {
    const int r = i >> 6, c = i & 63;   // r = t-local, c = d
    tile[r][c] = src[(size_t)(t0 + r) * (3 * DD) + c];
  }
  __syncthreads();
  unsigned short* dst = (unsigned short*)vt + (size_t)bh * 64 * SS + t0;
  for (int i = threadIdx.x; i < 4096; i += 256) {
    const int d = i >> 6, t = i & 63;
    dst[(size_t)d * SS + t] = tile[t][d];
  }
}

// ---------------- GEMM: bf16 A[M,K] x bf16 BT[N,K], 2-phase dbuf ----------------
template<bool RELU, bool OUT_BF16, bool HAS_RES>
__global__ __launch_bounds__(256) void gemm_bt(
    const __hip_bfloat16* __restrict__ A, const __hip_bfloat16* __restrict__ BT,
    const float* __restrict__ bias, const float* __restrict__ res,
    void* __restrict__ outp, int M, int N, int K)
{
  __shared__ __hip_bfloat16 Alds[2][128 * 32];
  __shared__ __hip_bfloat16 Blds[2][128 * 32];
  const int tid = threadIdx.x;
  const int wave = tid >> 6;
  const int lane = tid & 63;
  const int fr = lane & 15, fq = lane >> 4;
  const int wr = wave >> 1, wc = wave & 1;
  const int bm = blockIdx.y * 128, bn = blockIdx.x * 128;

  const int srow = tid >> 2;
  const int scol = (tid & 3) * 8;
  const __hip_bfloat16* ag0 = A + (size_t)(bm + srow) * K + scol;
  const __hip_bfloat16* ag1 = A + (size_t)(bm + 64 + srow) * K + scol;
  const __hip_bfloat16* bg0 = BT + (size_t)(bn + srow) * K + scol;
  const __hip_bfloat16* bg1 = BT + (size_t)(bn + 64 + srow) * K + scol;
  const int so = wave * 512;

  f32x4 acc[4][4] = {};

  async_copy16(ag0, &Alds[0][so]);
  async_copy16(ag1, &Alds[0][2048 + so]);
  async_copy16(bg0, &Blds[0][so]);
  async_copy16(bg1, &Blds[0][2048 + so]);
  __syncthreads();

  const int niter = K / 32;
  for (int i = 0; i < niter; ++i) {
    const int cur = i & 1;
    if (i + 1 < niter) {
      const int k1 = (i + 1) * 32;
      async_copy16(ag0 + k1, &Alds[cur ^ 1][so]);
      async_copy16(ag1 + k1, &Alds[cur ^ 1][2048 + so]);
      async_copy16(bg0 + k1, &Blds[cur ^ 1][so]);
      async_copy16(bg1 + k1, &Blds[cur ^ 1][2048 + so]);
    }
    bf16x8 af[4], bfr[4];
#pragma unroll
    for (int i4 = 0; i4 < 4; ++i4)
      af[i4] = *(const bf16x8*)(&Alds[cur][(wr * 64 + i4 * 16 + fr) * 32 + fq * 8]);
#pragma unroll
    for (int j4 = 0; j4 < 4; ++j4)
      bfr[j4] = *(const bf16x8*)(&Blds[cur][(wc * 64 + j4 * 16 + fr) * 32 + fq * 8]);
#pragma unroll
    for (int i4 = 0; i4 < 4; ++i4)
#pragma unroll
      for (int j4 = 0; j4 < 4; ++j4)
        acc[i4][j4] = __builtin_amdgcn_mfma_f32_16x16x32_bf16(af[i4], bfr[j4], acc[i4][j4], 0, 0, 0);
    __syncthreads();
  }

#pragma unroll
  for (int j = 0; j < 4; ++j) {
    const int c = bn + wc * 64 + j * 16 + fr;
    const float bv = bias[c];
#pragma unroll
    for (int i = 0; i < 4; ++i) {
#pragma unroll
      for (int r = 0; r < 4; ++r) {
        const int rr = bm + wr * 64 + i * 16 + fq * 4 + r;
        float v = acc[i][j][r] + bv;
        if (RELU) v = fmaxf(v, 0.0f);
        if (HAS_RES) v += res[(size_t)rr * N + c];
        if (OUT_BF16) ((__hip_bfloat16*)outp)[(size_t)rr * N + c] = __float2bfloat16(v);
        else          ((float*)outp)[(size_t)rr * N + c] = v;
      }
    }
  }
}

// ---------------- Split-K GEMM partial (2-phase dbuf): fp32 partial ----------------
__global__ __launch_bounds__(256) void gemm_bt_sk(
    const __hip_bfloat16* __restrict__ A, const __hip_bfloat16* __restrict__ BT,
    float* __restrict__ part01, float* __restrict__ part23,
    int M, int N, int K, int K_per)
{
  __shared__ __hip_bfloat16 Alds[2][128 * 32];
  __shared__ __hip_bfloat16 Blds[2][128 * 32];
  const int tid = threadIdx.x;
  const int wave = tid >> 6;
  const int lane = tid & 63;
  const int fr = lane & 15, fq = lane >> 4;
  const int wr = wave >> 1, wc = wave & 1;
  const int bm = blockIdx.y * 128, bn = blockIdx.x * 128;
  const int z = blockIdx.z;
  float* part = (z < 2 ? part01 : part23) + (size_t)(z & 1) * M * N;
  const int kbase = z * K_per;

  const int srow = tid >> 2;
  const int scol = (tid & 3) * 8;
  const __hip_bfloat16* ag0 = A + (size_t)(bm + srow) * K + scol + kbase;
  const __hip_bfloat16* ag1 = A + (size_t)(bm + 64 + srow) * K + scol + kbase;
  const __hip_bfloat16* bg0 = BT + (size_t)(bn + srow) * K + scol + kbase;
  const __hip_bfloat16* bg1 = BT + (size_t)(bn + 64 + srow) * K + scol + kbase;
  const int so = wave * 512;

  f32x4 acc[4][4] = {};

  async_copy16(ag0, &Alds[0][so]);
  async_copy16(ag1, &Alds[0][2048 + so]);
  async_copy16(bg0, &Blds[0][so]);
  async_copy16(bg1, &Blds[0][2048 + so]);
  __syncthreads();

  const int niter = K_per / 32;
  for (int i = 0; i < niter; ++i) {
    const int cur = i & 1;
    if (i + 1 < niter) {
      const int k1 = (i + 1) * 32;
      async_copy16(ag0 + k1, &Alds[cur ^ 1][so]);
      async_copy16(ag1 + k1, &Alds[cur ^ 1][2048 + so]);
      async_copy16(bg0 + k1, &Blds[cur ^ 1][so]);
      async_copy16(bg1 + k1, &Blds[cur ^ 1][2048 + so]);
    }
    bf16x8 af[4], bfr[4];
#pragma unroll
    for (int i4 = 0; i4 < 4; ++i4)
      af[i4] = *(const bf16x8*)(&Alds[cur][(wr * 64 + i4 * 16 + fr) * 32 + fq * 8]);
#pragma unroll
    for (int j4 = 0; j4 < 4; ++j4)
      bfr[j4] = *(const bf16x8*)(&Blds[cur][(wc * 64 + j4 * 16 + fr) * 32 + fq * 8]);
#pragma unroll
    for (int i4 = 0; i4 < 4; ++i4)
#pragma unroll
      for (int j4 = 0; j4 < 4; ++j4)
        acc[i4][j4] = __builtin_amdgcn_mfma_f32_16x16x32_bf16(af[i4], bfr[j4], acc[i4][j4], 0, 0, 0);
    __syncthreads();
  }

#pragma unroll
  for (int j = 0; j < 4; ++j) {
    const int c = bn + wc * 64 + j * 16 + fr;
#pragma unroll
    for (int i = 0; i < 4; ++i) {
#pragma unroll
      for (int r = 0; r < 4; ++r) {
        const int rr = bm + wr * 64 + i * 16 + fq * 4 + r;
        part[(size_t)rr * N + c] = acc[i][j][r];
      }
    }
  }
}

// ---------------- combine 4 split-K partials + bias + residual -> fp32 ----------------
__global__ __launch_bounds__(256) void combine4(
    const float* __restrict__ part01, const float* __restrict__ part23,
    const float* __restrict__ res, const float* __restrict__ bias,
    float* __restrict__ out, int MN, int N)
{
  const int idx = (blockIdx.x * 256 + threadIdx.x) * 4;
  if (idx >= MN) return;
  const float4 a0 = *(const float4*)(part01 + idx);
  const float4 a1 = *(const float4*)(part01 + MN + idx);
  const float4 a2 = *(const float4*)(part23 + idx);
  const float4 a3 = *(const float4*)(part23 + MN + idx);
  const float4 rr = *(const float4*)(res + idx);
  const float4 bb = *(const float4*)(bias + (idx % N));
  float4 o;
  o.x = a0.x + a1.x + a2.x + a3.x + rr.x + bb.x;
  o.y = a0.y + a1.y + a2.y + a3.y + rr.y + bb.y;
  o.z = a0.z + a1.z + a2.z + a3.z + rr.z + bb.z;
  o.w = a0.w + a1.w + a2.w + a3.w + rr.w + bb.w;
  *(float4*)(out + idx) = o;
}

// ---------------- Flash attention, swapped-QK^T 32x32 ----------------
// 768 blocks x 256 threads (4 warps). XCD decode: xcd=id&7 owns 3 heads;
// q-block p (0..31) covers 64 q rows = TWO 32-row strips (warp pairs).
// Within a strip the 2 warps split KV tiles mod 2 with private (m,l,O),
// LSE-combined via LDS. V comes PRE-TRANSPOSED (VT [bh][64][2048]) so both
// K and V stage as coalesced bf16x8 copies into XOR-swizzled LDS.
__global__ __launch_bounds__(256, 4) void attn_kernel(
    const __hip_bfloat16* __restrict__ qkv, const __hip_bfloat16* __restrict__ vtg,
    __hip_bfloat16* __restrict__ outp)
{
  const int HD = 3 * DD;   // 2304
  const int id = blockIdx.x;
  const int xcd = id & 7;
  const int j = id >> 3;              // 0..95 within XCD
  const int bh_l = j >> 5;            // 0..2
  const int c32 = j & 31;             // q-block within head, 0..31
  const int p = (bh_l == 0) ? (31 - c32)
              : (bh_l == 1) ? c32
                            : (31 - ((c32 + 16) & 31));
  const int bh = xcd * 3 + bh_l;      // 24 heads = 8 XCD x 3
  const int b = bh / HH, h = bh - (bh / HH) * HH;

  const int q0A = p * 64;             // block covers q in [q0A, q0A+64)
  const int tid = threadIdx.x, w = tid >> 6, lane = tid & 63;
  const int sidx = w >> 1;            // strip 0/1
  const int c = w & 1;                // kv-split index 0/1
  const int col = lane & 31, hi = lane >> 5;
  const int q0w = q0A + 32 * sidx;
  const int qg = q0w + col;

  const size_t base = (size_t)b * SS * HD;
  const __hip_bfloat16* Qp = qkv + base + h * DHH;
  const __hip_bfloat16* Kp = qkv + base + DD + h * DHH;
  const __hip_bfloat16* VTp = vtg + (size_t)bh * 64 * SS;   // [d][t]

  // LDS: 2 x 8KB swizzled Vt + 2 x 8KB swizzled K = 32KB.
  // Epilogue reuses [0,17152): opart[2][32][65] f32 + ml[2][2][32] f32.
  __shared__ __align__(16) char sm[32768];
  char* const smV = sm;
  char* const smK = sm + 16384;

  bf16x8 qf[4];
#pragma unroll
  for (int kc = 0; kc < 4; ++kc)
    qf[kc] = *(const bf16x8*)(Qp + (size_t)qg * HD + kc * 16 + hi * 8);

  f32x16 o0 = {}, o1 = {};
  float mreg = -1e30f, lreg = 0.f;
  const float CS = 0.125f * 1.44269504f;

  // staging (identical pattern for K rows and VT rows): row = tid>>3 (+32),
  // 16B chunk = (tid&7)*8 elements
  const int kr = tid >> 3;                      // 0..31
  const int kd8 = (tid & 7) * 8;
  const int kswz0 = (kr * 128 + kd8 * 2) ^ ((kr & 7) << 4);
  const int kswz1 = kswz0 + 32 * 128;           // (kr+32)&7 == kr&7

  const int ntiles = p + 1;                     // same for both strips
  const int nrounds = (ntiles + 1) >> 1;
  char* const vt_c = smV + c * 8192;
  char* const kt_c = smK + c * 8192;

  for (int jr = 0; jr < nrounds; ++jr) {
    __syncthreads();
#pragma unroll
    for (int tt = 0; tt < 2; ++tt) {
      const int tw = 2 * jr + tt;
      if (tw < ntiles) {
        const int kv0 = tw * 64;
        // V^T rows (d = kr, kr+32), coalesced 16B
        *(bf16x8*)(smV + tt * 8192 + kswz0) =
            *(const bf16x8*)(VTp + (size_t)kr * SS + kv0 + kd8);
        *(bf16x8*)(smV + tt * 8192 + kswz1) =
            *(const bf16x8*)(VTp + (size_t)(kr + 32) * SS + kv0 + kd8);
        // K rows, coalesced 16B
        *(bf16x8*)(smK + tt * 8192 + kswz0) =
            *(const bf16x8*)(Kp + (size_t)(kv0 + kr) * HD + kd8);
        *(bf16x8*)(smK + tt * 8192 + kswz1) =
            *(const bf16x8*)(Kp + (size_t)(kv0 + 32 + kr) * HD + kd8);
      }
    }
    __syncthreads();

    const int tw = 2 * jr + c;
    if (tw < ntiles) {
      const int kv0 = tw * 64;
      f32x16 s0 = {}, s1 = {};
#pragma unroll
      for (int kc = 0; kc < 4; ++kc) {
        const int koff2 = (kc * 16 + hi * 8) * 2;
        bf16x8 k0 = *(const bf16x8*)&kt_c[(col * 128 + koff2) ^ ((col & 7) << 4)];
        bf16x8 k1 = *(const bf16x8*)&kt_c[((32 + col) * 128 + koff2) ^ ((col & 7) << 4)];
        s0 = __builtin_amdgcn_mfma_f32_32x32x16_bf16(k0, qf[kc], s0, 0, 0, 0);
        s1 = __builtin_amdgcn_mfma_f32_32x32x16_bf16(k1, qf[kc], s1, 0, 0, 0);
      }
      if (kv0 + 63 > q0w) {
#pragma unroll
        for (int r = 0; r < 16; ++r) {
          const int tl = (r & 3) + 8 * (r >> 2) + 4 * hi;
          s0[r] = (kv0 + tl <= qg) ? s0[r] : -1e30f;
          s1[r] = (kv0 + 32 + tl <= qg) ? s1[r] : -1e30f;
        }
      }
      float mx = s0[0];
#pragma unroll
      for (int r = 1; r < 16; ++r) mx = fmaxf(mx, s0[r]);
#pragma unroll
      for (int r = 0; r < 16; ++r) mx = fmaxf(mx, s1[r]);
      mx = fmaxf(mx, __shfl_xor(mx, 32));
      const float mnew = fmaxf(mreg, mx);
      const float alpha = exp2f((mreg - mnew) * CS);
      mreg = mnew;
      const float mc = mnew * CS;
      float ps = 0.f;
#pragma unroll
      for (int r = 0; r < 16; ++r) {
        const float p0 = exp2f(s0[r] * CS - mc); s0[r] = p0; ps += p0;
        const float p1 = exp2f(s1[r] * CS - mc); s1[r] = p1; ps += p1;
      }
      ps += __shfl_xor(ps, 32);
      lreg = lreg * alpha + ps;
#pragma unroll
      for (int r = 0; r < 16; ++r) { o0[r] *= alpha; o1[r] *= alpha; }

      u32 pk0[4][2], pk1[4][2];
#pragma unroll
      for (int qd = 0; qd < 4; ++qd) {
        pk0[qd][0] = pack2(s0[4 * qd + 0], s0[4 * qd + 1]);
        pk0[qd][1] = pack2(s0[4 * qd + 2], s0[4 * qd + 3]);
        pk1[qd][0] = pack2(s1[4 * qd + 0], s1[4 * qd + 1]);
        pk1[qd][1] = pack2(s1[4 * qd + 2], s1[4 * qd + 3]);
      }
#pragma unroll
      for (int kc = 0; kc < 4; ++kc) {
        const int qa = 2 * (kc & 1), qb = qa + 1;
        const u32 A0 = (kc < 2) ? pk0[qa][0] : pk1[qa][0];
        const u32 A1 = (kc < 2) ? pk0[qa][1] : pk1[qa][1];
        const u32 B0 = (kc < 2) ? pk0[qb][0] : pk1[qb][0];
        const u32 B1 = (kc < 2) ? pk0[qb][1] : pk1[qb][1];
        const u32 send0 = hi ? A0 : B0;
        const u32 send1 = hi ? A1 : B1;
        const u32 recv0 = __shfl_xor(send0, 32);
        const u32 recv1 = __shfl_xor(send1, 32);
        const u32 su0 = hi ? B0 : A0;
        const u32 su1 = hi ? B1 : A1;
        union { u32 u[4]; bf16x8 v; } pf;
        pf.u[0] = hi ? recv0 : su0;
        pf.u[1] = hi ? recv1 : su1;
        pf.u[2] = hi ? su0 : recv0;
        pf.u[3] = hi ? su1 : recv1;
        const int toff2 = (kc * 16 + hi * 8) * 2;
        const int d0 = col, d1 = 32 + col;
        bf16x8 vfa = *(const bf16x8*)&vt_c[(d0 * 128 + toff2) ^ ((d0 & 7) << 4)];
        bf16x8 vfb = *(const bf16x8*)&vt_c[(d1 * 128 + toff2) ^ ((d1 & 7) << 4)];
        o0 = __builtin_amdgcn_mfma_f32_32x32x16_bf16(vfa, pf.v, o0, 0, 0, 0);
        o1 = __builtin_amdgcn_mfma_f32_32x32x16_bf16(vfb, pf.v, o1, 0, 0, 0);
      }
    }
  }

  // ---- combine the 2 kv-split partials per strip (2 LDS phases) ----
  float* opart = (float*)sm;                 // [2][32][65]
  float* mlp   = (float*)(sm + 16640);       // [c][0][q]=m, [c][1][q]=l
#pragma unroll
  for (int s = 0; s < 2; ++s) {
    __syncthreads();
    if (sidx == s) {
#pragma unroll
      for (int r = 0; r < 16; ++r) {
        const int d = (r & 3) + 8 * (r >> 2) + 4 * hi;
        opart[(c * 32 + col) * 65 + d]      = o0[r];
        opart[(c * 32 + col) * 65 + d + 32] = o1[r];
      }
      if (hi == 0) {
        mlp[c * 64 + col]      = mreg;
        mlp[c * 64 + 32 + col] = lreg;
      }
    }
    __syncthreads();
    const int q = tid >> 3;            // 0..31
    const int d0 = (tid & 7) * 8;      // 0..56
    float mcv[2], lcv[2];
#pragma unroll
    for (int cc = 0; cc < 2; ++cc) {
      mcv[cc] = mlp[cc * 64 + q];
      lcv[cc] = mlp[cc * 64 + 32 + q];
    }
    const float mstar = fmaxf(mcv[0], mcv[1]);
    float av[2], lstar = 0.f;
#pragma unroll
    for (int cc = 0; cc < 2; ++cc) {
      av[cc] = exp2f((mcv[cc] - mstar) * CS);
      lstar += av[cc] * lcv[cc];
    }
    const float inv = 1.0f / lstar;
    float acc[8] = {};
#pragma unroll
    for (int cc = 0; cc < 2; ++cc) {
      const float a = av[cc];
#pragma unroll
      for (int e = 0; e < 8; ++e)
        acc[e] += a * opart[(cc * 32 + q) * 65 + d0 + e];
    }
    u16x8 w8;
#pragma unroll
    for (int e = 0; e < 8; ++e) w8[e] = bf16bits(acc[e] * inv);
    unsigned short* orow = (unsigned short*)outp +
        (size_t)(b * SS + q0A + 32 * s + q) * DD + h * DHH + d0;
    *(u16x8*)orow = w8;
  }
}

// ---------------- host ----------------
extern "C" void kernel_launch(void* const* d_in, const int* in_sizes, int n_in,
                              void* d_out, int out_size, void* d_ws, size_t ws_size,
                              hipStream_t stream)
{
  (void)in_sizes; (void)n_in; (void)out_size; (void)ws_size;
  const float* X  = (const float*)d_in[0];
  const float* Wq = (const float*)d_in[1];
  const float* bq = (const float*)d_in[2];
  const float* Wk = (const float*)d_in[3];
  const float* bk = (const float*)d_in[4];
  const float* Wv = (const float*)d_in[5];
  const float* bv = (const float*)d_in[6];
  const float* W0 = (const float*)d_in[7];
  const float* b0 = (const float*)d_in[8];
  const float* W1 = (const float*)d_in[9];
  const float* b1 = (const float*)d_in[10];
  const float* W2 = (const float*)d_in[11];
  const float* b2 = (const float*)d_in[12];
  const float* g1 = (const float*)d_in[13];
  const float* o1 = (const float*)d_in[14];
  const float* g2 = (const float*)d_in[15];
  const float* o2 = (const float*)d_in[16];

  char* ws = (char*)d_ws;
  auto alloc = [&](size_t bytes) {
    char* p = ws;
    ws += (bytes + 255) & ~(size_t)255;
    return p;
  };
  __hip_bfloat16* ln1    = (__hip_bfloat16*)alloc((size_t)MM * DD * 2);
  __hip_bfloat16* qkvb16 = (__hip_bfloat16*)alloc((size_t)MM * 3 * DD * 2);
  __hip_bfloat16* attnb  = (__hip_bfloat16*)alloc((size_t)MM * DD * 2);
  float*          hbuf   = (float*)alloc((size_t)MM * DD * 4);
  __hip_bfloat16* ln2    = (__hip_bfloat16*)alloc((size_t)MM * DD * 2);
  __hip_bfloat16* ffn1   = (__hip_bfloat16*)alloc((size_t)MM * DFF * 2);
  __hip_bfloat16* WqkvT  = (__hip_bfloat16*)alloc((size_t)3 * DD * DD * 2);
  __hip_bfloat16* W0T    = (__hip_bfloat16*)alloc((size_t)DD * DD * 2);
  __hip_bfloat16* W1T    = (__hip_bfloat16*)alloc((size_t)DFF * DD * 2);
  __hip_bfloat16* W2T    = (__hip_bfloat16*)alloc((size_t)DD * DFF * 2);
  float*          qkvbias= (float*)alloc((size_t)3 * DD * 4);
  float*          part23 = (float*)alloc((size_t)2 * MM * DD * 4);  // splits 2,3
  __hip_bfloat16* vtbuf  = (__hip_bfloat16*)alloc((size_t)MM * DD * 2);  // V^T [bh][64][2048]
  // splits 0,1 alias [ln1, qkvb16] (exactly 2*MM*DD*4 bytes, both dead by FFN2)
  float*          part01 = (float*)ln1;

  transpose_qkv<<<dim3(1, 12, 36), 256, 0, stream>>>(Wq, Wk, Wv, WqkvT);
  transpose_generic<<<dim3(12, 12), 256, 0, stream>>>(W0, W0T, DD, DD);
  transpose_generic<<<dim3(48, 12), 256, 0, stream>>>(W1, W1T, DD, DFF);
  transpose_generic<<<dim3(12, 48), 256, 0, stream>>>(W2, W2T, DFF, DD);
  hipMemcpyAsync(qkvbias,          bq, DD * 4, hipMemcpyDeviceToDevice, stream);
  hipMemcpyAsync(qkvbias + DD,     bk, DD * 4, hipMemcpyDeviceToDevice, stream);
  hipMemcpyAsync(qkvbias + 2 * DD, bv, DD * 4, hipMemcpyDeviceToDevice, stream);

  ln_kernel<<<MM / 4, 256, 0, stream>>>(X, g1, o1, ln1);
  gemm_bt<false, true, false><<<dim3(3 * DD / 128, MM / 128), 256, 0, stream>>>(
      ln1, WqkvT, qkvbias, nullptr, qkvb16, MM, 3 * DD, DD);
  vtrans_kernel<<<dim3(SS / 64, BB * HH), 256, 0, stream>>>(qkvb16, vtbuf);
  attn_kernel<<<768, 256, 0, stream>>>(qkvb16, vtbuf, attnb);
  gemm_bt<false, false, true><<<dim3(DD / 128, MM / 128), 256, 0, stream>>>(
      attnb, W0T, b0, X, hbuf, MM, DD, DD);
  ln_kernel<<<MM / 4, 256, 0, stream>>>(hbuf, g2, o2, ln2);
  gemm_bt<true, true, false><<<dim3(DFF / 128, MM / 128), 256, 0, stream>>>(
      ln2, W1T, b1, nullptr, ffn1, MM, DFF, DD);
  // FFN2 via split-K=4: partials then combine(+bias+residual)
  gemm_bt_sk<<<dim3(DD / 128, MM / 128, 4), 256, 0, stream>>>(
      ffn1, W2T, part01, part23, MM, DD, DFF, DFF / 4);
  combine4<<<(MM * DD) / 1024, 256, 0, stream>>>(
      part01, part23, hbuf, b2, (float*)d_out, MM * DD, DD);
}